// Round 15
// baseline (1192.367 us; speedup 1.0000x reference)
//
#include <hip/hip_runtime.h>
#include <stdint.h>

#define NTOK 16384        // B*D*L = 8*16*128
#define HDIM 512
#define FDIM 4096
#define NHEAD 8
#define QKVD 1536         // fused QKV row width

typedef __attribute__((ext_vector_type(8))) _Float16 f16x8;
typedef __attribute__((ext_vector_type(16))) float f32x16;
#define LOSCALE 4096.0f
#define LOINV   (1.0f / 4096.0f)

static __device__ __forceinline__ void ld8f(const float* p, float* v) {
    *(float4*)&v[0] = *(const float4*)p;
    *(float4*)&v[4] = *(const float4*)(p + 4);
}
static __device__ __forceinline__ void st8f(float* p, const float* v) {
    *(float4*)p       = *(const float4*)&v[0];
    *(float4*)(p + 4) = *(const float4*)&v[4];
}

// ---- x0 = concat(query_token, zL[:, :-1]) -> f32 ----
__global__ __launch_bounds__(256) void build_x_k(const float* __restrict__ zL,
                                                 const float* __restrict__ qt,
                                                 float* __restrict__ X) {
    int idx = blockIdx.x * 256 + threadIdx.x;
    int n = idx >> 6;
    int h = (idx & 63) << 3;
    int d = (n >> 7) & 15;
    const float* src = d ? (zL + (((size_t)(n - 128)) << 9) + h) : (qt + h);
    float v[8];
    ld8f(src, v);
    st8f(X + (((size_t)n) << 9) + h, v);
}

// ---- fused LN stats + LN + fp16 2-way split (one wave per row) ----
__global__ __launch_bounds__(256) void ln_split_k(const float* __restrict__ X,
                                                  const float* __restrict__ gamma,
                                                  const float* __restrict__ beta,
                                                  _Float16* __restrict__ ph,
                                                  _Float16* __restrict__ pl) {
    int row = blockIdx.x * 4 + (threadIdx.x >> 6);
    int lane = threadIdx.x & 63;
    int h = lane << 3;
    const float* xr = X + (((size_t)row) << 9) + h;
    float v[8];
    ld8f(xr, v);
    float s = 0.f;
#pragma unroll
    for (int i = 0; i < 8; ++i) s += v[i];
#pragma unroll
    for (int off = 32; off; off >>= 1) s += __shfl_xor(s, off);
    float m = s * (1.0f / 512.0f);
    float q = 0.f;
#pragma unroll
    for (int i = 0; i < 8; ++i) { float d = v[i] - m; q += d * d; }
#pragma unroll
    for (int off = 32; off; off >>= 1) q += __shfl_xor(q, off);
    float rs = 1.0f / sqrtf(q * (1.0f / 512.0f) + 1e-5f);
    float gv[8], be[8];
    ld8f(gamma + h, gv);
    ld8f(beta + h, be);
    _Float16 h8[8], l8[8];
#pragma unroll
    for (int i = 0; i < 8; ++i) {
        float y = (v[i] - m) * rs * gv[i] + be[i];
        _Float16 hh = (_Float16)y;
        h8[i] = hh;
        l8[i] = (_Float16)((y - (float)hh) * LOSCALE);
    }
    size_t off = (((size_t)row) << 9) + h;
    *(int4*)(ph + off) = *(int4*)h8;
    *(int4*)(pl + off) = *(int4*)l8;
}

// ---- non-causal attention over L; QKV interleaved [n][1536]; OUT fp16 split -
__global__ __launch_bounds__(512) void attn_l_k(const float* __restrict__ QKV,
                                                _Float16* __restrict__ xh,
                                                _Float16* __restrict__ xl) {
    __shared__ float ks[128][64];
    __shared__ float vs[128][64];
    const int seq = blockIdx.x, head = blockIdx.y;
    const int t = threadIdx.x;
    const size_t tok0 = (size_t)seq << 7;      // first token of this sequence
    const int ho = head << 6;
#pragma unroll
    for (int i = 0; i < 4; ++i) {
        int slot = t + (i << 9);
        int row = slot >> 4;
        int c4 = (slot & 15) << 2;
        size_t g = (tok0 + row) * QKVD + ho + c4;
        *(float4*)&ks[row][c4] = *(const float4*)(QKV + g + 512);
        *(float4*)&vs[row][c4] = *(const float4*)(QKV + g + 1024);
    }
    __syncthreads();
    const int r = t >> 2;
    const int q16 = (t & 3) << 4;
    const float* qp = QKV + (tok0 + r) * QKVD + ho + q16;
    float qr[16];
#pragma unroll
    for (int i = 0; i < 4; ++i) *(float4*)&qr[i << 2] = *(const float4*)(qp + (i << 2));
    float o[16];
#pragma unroll
    for (int d = 0; d < 16; ++d) o[d] = 0.f;
    float m = -1e30f, l = 0.f;
    for (int j = 0; j < 128; ++j) {
        const float* kp = &ks[j][q16];
        float s0 = 0.f, s1 = 0.f, s2 = 0.f, s3 = 0.f;
#pragma unroll
        for (int d = 0; d < 16; d += 4) {
            s0 = fmaf(qr[d + 0], kp[d + 0], s0);
            s1 = fmaf(qr[d + 1], kp[d + 1], s1);
            s2 = fmaf(qr[d + 2], kp[d + 2], s2);
            s3 = fmaf(qr[d + 3], kp[d + 3], s3);
        }
        float sp = (s0 + s1) + (s2 + s3);
        sp += __shfl_xor(sp, 1);
        sp += __shfl_xor(sp, 2);
        float s = sp * 0.125f;
        if (s > m) {
            float c = expf(m - s);
#pragma unroll
            for (int d = 0; d < 16; ++d) o[d] *= c;
            l *= c;
            m = s;
        }
        float w = expf(s - m);
        l += w;
        const float* vp = &vs[j][q16];
#pragma unroll
        for (int d = 0; d < 16; ++d) o[d] = fmaf(w, vp[d], o[d]);
    }
    float inv = 1.0f / l;
    _Float16 h8[16], l8[16];
#pragma unroll
    for (int i = 0; i < 16; ++i) {
        float y = o[i] * inv;
        _Float16 hh = (_Float16)y;
        h8[i] = hh;
        l8[i] = (_Float16)((y - (float)hh) * LOSCALE);
    }
    size_t eo = ((tok0 + r) << 9) + ho + q16;
    *(int4*)(xh + eo)     = ((int4*)h8)[0];
    *(int4*)(xh + eo + 8) = ((int4*)h8)[1];
    *(int4*)(xl + eo)     = ((int4*)l8)[0];
    *(int4*)(xl + eo + 8) = ((int4*)l8)[1];
}

// ---- causal attention over D; QKV interleaved [n][1536]; OUT fp16 split ----
__global__ __launch_bounds__(128) void attn_d_k(const float* __restrict__ QKV,
                                                _Float16* __restrict__ xh,
                                                _Float16* __restrict__ xl) {
    __shared__ float ks[16][512];
    __shared__ float vs[16][512];
    const int bl = blockIdx.x;
    const int b = bl >> 7, l = bl & 127;
    const int t = threadIdx.x;
    const size_t tok0 = (size_t)b * 2048 + l;   // token at depth 0
#pragma unroll
    for (int i = 0; i < 16; ++i) {
        int c4 = t << 2;
        size_t g = (tok0 + (size_t)i * 128) * QKVD + c4;
        *(float4*)&ks[i][c4] = *(const float4*)(QKV + g + 512);
        *(float4*)&vs[i][c4] = *(const float4*)(QKV + g + 1024);
    }
    __syncthreads();
    const int head = t >> 4, dr = t & 15;
    const int ho = head << 6;
    float qr[64];
    const float* qp = QKV + (tok0 + (size_t)dr * 128) * QKVD + ho;
#pragma unroll
    for (int i = 0; i < 16; ++i) *(float4*)&qr[i << 2] = *(const float4*)(qp + (i << 2));
    float s[16];
    float m = -1e30f;
#pragma unroll
    for (int j = 0; j < 16; ++j) {
        float s0 = 0.f, s1 = 0.f, s2 = 0.f, s3 = 0.f;
#pragma unroll
        for (int d = 0; d < 64; d += 4) {
            s0 = fmaf(qr[d + 0], ks[j][ho + d + 0], s0);
            s1 = fmaf(qr[d + 1], ks[j][ho + d + 1], s1);
            s2 = fmaf(qr[d + 2], ks[j][ho + d + 2], s2);
            s3 = fmaf(qr[d + 3], ks[j][ho + d + 3], s3);
        }
        float sv = ((s0 + s1) + (s2 + s3)) * 0.125f;
        s[j] = (j <= dr) ? sv : -1e30f;
        m = fmaxf(m, s[j]);
    }
    float lsum = 0.f;
#pragma unroll
    for (int j = 0; j < 16; ++j) {
        float w = (j <= dr) ? expf(s[j] - m) : 0.f;
        s[j] = w;
        lsum += w;
    }
    float inv = 1.0f / lsum;
    float o[64];
#pragma unroll
    for (int d = 0; d < 64; ++d) o[d] = 0.f;
#pragma unroll
    for (int j = 0; j < 16; ++j) {
        float w = s[j];
#pragma unroll
        for (int d = 0; d < 64; ++d) o[d] = fmaf(w, vs[j][ho + d], o[d]);
    }
    size_t eo = ((tok0 + (size_t)dr * 128) << 9) + ho;
#pragma unroll
    for (int i = 0; i < 8; ++i) {
        _Float16 h8[8], l8[8];
#pragma unroll
        for (int j = 0; j < 8; ++j) {
            float y = o[i * 8 + j] * inv;
            _Float16 hh = (_Float16)y;
            h8[j] = hh;
            l8[j] = (_Float16)((y - (float)hh) * LOSCALE);
        }
        *(int4*)(xh + eo + (i << 3)) = *(int4*)h8;
        *(int4*)(xl + eo + (i << 3)) = *(int4*)l8;
    }
}

// ---- fused: out_xp = x; split(zL - x - bias_pre) -> xh/xl ----
__global__ __launch_bounds__(256) void xprior_xsrc_k(const float* __restrict__ zL,
                                                     const float* __restrict__ bias_pre,
                                                     const float* __restrict__ X,
                                                     float* __restrict__ out_xp,
                                                     _Float16* __restrict__ xh,
                                                     _Float16* __restrict__ xl) {
    int idx = blockIdx.x * 256 + threadIdx.x;
    int h = (idx & 63) << 3;
    size_t off = ((size_t)idx) << 3;
    float z[8], p[8], x[8];
    ld8f(zL + off, z);
    ld8f(bias_pre + h, p);
    ld8f(X + off, x);
    st8f(out_xp + off, x);
    _Float16 h8[8], l8[8];
#pragma unroll
    for (int i = 0; i < 8; ++i) {
        float y = z[i] - x[i] - p[i];
        _Float16 hh = (_Float16)y;
        h8[i] = hh;
        l8[i] = (_Float16)((y - (float)hh) * LOSCALE);
    }
    *(int4*)(xh + off) = *(int4*)h8;
    *(int4*)(xl + off) = *(int4*)l8;
}

// ---- 2-way fp16 scaled split: x = h + l*2^-12 ----
__global__ __launch_bounds__(256) void split2_k(const float* __restrict__ in,
                                                _Float16* __restrict__ ph,
                                                _Float16* __restrict__ pl) {
    int idx = blockIdx.x * 256 + threadIdx.x;
    float v[8];
    ld8f(in + (((size_t)idx) << 3), v);
    _Float16 h8[8], l8[8];
#pragma unroll
    for (int i = 0; i < 8; ++i) {
        _Float16 h = (_Float16)v[i];
        float r = v[i] - (float)h;          // exact
        h8[i] = h;
        l8[i] = (_Float16)(r * LOSCALE);
    }
    *(int4*)(ph + (((size_t)idx) << 3)) = *(int4*)h8;
    *(int4*)(pl + (((size_t)idx) << 3)) = *(int4*)l8;
}

// ---- 3-pass split-fp16 MFMA NT GEMM, 32x32x16, 128x64 tile, 2-phase dbuf ---
// (unchanged from round 14 — twice-validated at absmax floor)
#define LDT 34
template<bool ADD_C, bool BIAS>
__global__ __launch_bounds__(256) void gemm_f16_k(
        const _Float16* __restrict__ Xh, const _Float16* __restrict__ Xl,
        const _Float16* __restrict__ Wh, const _Float16* __restrict__ Wl,
        const float* __restrict__ bias, float* __restrict__ Cout, int ldc) {
    __shared__ _Float16 Ah[2][128][LDT], Al[2][128][LDT];
    __shared__ _Float16 Bh[2][64][LDT],  Bl[2][64][LDT];
    const int tid = threadIdx.x;
    const int bm = blockIdx.y << 7;      // 128-row tile
    const int bn = blockIdx.x << 6;      // 64-col tile
    const int w = tid >> 6, lane = tid & 63;
    const int wr = w >> 1, wc = w & 1;
    const int l31 = lane & 31, hh = lane >> 5;
    const int ar0 = tid >> 2, akg = (tid & 3) << 3;
    const int ar1 = ar0 + 64;
    const _Float16* pXh0 = Xh + (size_t)(bm + ar0) * HDIM + akg;
    const _Float16* pXl0 = Xl + (size_t)(bm + ar0) * HDIM + akg;
    const _Float16* pXh1 = Xh + (size_t)(bm + ar1) * HDIM + akg;
    const _Float16* pXl1 = Xl + (size_t)(bm + ar1) * HDIM + akg;
    const _Float16* pWh  = Wh + (size_t)(bn + ar0) * HDIM + akg;
    const _Float16* pWl  = Wl + (size_t)(bn + ar0) * HDIM + akg;

    f32x16 acc1[2], acc2[2];
#pragma unroll
    for (int i = 0; i < 2; ++i)
#pragma unroll
        for (int r = 0; r < 16; ++r) { acc1[i][r] = 0.f; acc2[i][r] = 0.f; }

    int4 ra0h, ra0l, ra1h, ra1l, rbh, rbl;
    auto LOADR = [&](int k0) {
        ra0h = *(const int4*)(pXh0 + k0);
        ra0l = *(const int4*)(pXl0 + k0);
        ra1h = *(const int4*)(pXh1 + k0);
        ra1l = *(const int4*)(pXl1 + k0);
        rbh  = *(const int4*)(pWh + k0);
        rbl  = *(const int4*)(pWl + k0);
    };
    auto STORE = [&](int buf) {
        *(int4*)&Ah[buf][ar0][akg] = ra0h;
        *(int4*)&Al[buf][ar0][akg] = ra0l;
        *(int4*)&Ah[buf][ar1][akg] = ra1h;
        *(int4*)&Al[buf][ar1][akg] = ra1l;
        *(int4*)&Bh[buf][ar0][akg] = rbh;
        *(int4*)&Bl[buf][ar0][akg] = rbl;
    };

    LOADR(0);
    STORE(0);
    int cur = 0;
    for (int it = 0; it < 16; ++it) {
        if (it < 15) LOADR((it + 1) << 5);
        __syncthreads();
#pragma unroll
        for (int kh = 0; kh < 2; ++kh) {
            const int ko = (kh << 4) + (hh << 3);
            f16x8 fah[2], fal[2];
#pragma unroll
            for (int mf = 0; mf < 2; ++mf) {
                int ar = (wr << 6) + (mf << 5) + l31;
                fah[mf] = *(const f16x8*)&Ah[cur][ar][ko];
                fal[mf] = *(const f16x8*)&Al[cur][ar][ko];
            }
            int bc_ = (wc << 5) + l31;
            f16x8 bh = *(const f16x8*)&Bh[cur][bc_][ko];
            f16x8 bl = *(const f16x8*)&Bl[cur][bc_][ko];
#pragma unroll
            for (int mf = 0; mf < 2; ++mf) {
                acc1[mf] = __builtin_amdgcn_mfma_f32_32x32x16_f16(fah[mf], bh, acc1[mf], 0, 0, 0);
                acc2[mf] = __builtin_amdgcn_mfma_f32_32x32x16_f16(fah[mf], bl, acc2[mf], 0, 0, 0);
                acc2[mf] = __builtin_amdgcn_mfma_f32_32x32x16_f16(fal[mf], bh, acc2[mf], 0, 0, 0);
            }
        }
        if (it < 15) { STORE(cur ^ 1); cur ^= 1; }
    }
    const int col = bn + (wc << 5) + l31;
    const float badd = BIAS ? bias[col] : 0.f;
#pragma unroll
    for (int mf = 0; mf < 2; ++mf) {
#pragma unroll
        for (int r = 0; r < 16; ++r) {
            int row = bm + (wr << 6) + (mf << 5) + (r & 3) + ((r >> 2) << 3) + (hh << 2);
            float* cp = Cout + (size_t)row * ldc + col;
            float val = acc1[mf][r] + acc2[mf][r] * LOINV + badd;
            if (ADD_C) val += *cp;
            *cp = val;
        }
    }
}

// ---- per-row top-64: relu + exact radix select (early-exit) + scatter ----
__global__ __launch_bounds__(256) void topk_k(const float* __restrict__ logits,
                                              float* __restrict__ out) {
    const int row = blockIdx.x;
    const float* lr = logits + (((size_t)row) << 12);
    const int t = threadIdx.x;
    float v[16]; uint32_t u[16];
#pragma unroll
    for (int i = 0; i < 16; ++i) {
        float x = fmaxf(lr[t + (i << 8)], 0.f);
        v[i] = x;
        u[i] = __float_as_uint(x);
    }
    __shared__ int red[4];
    __shared__ unsigned long long bits[64];
    __shared__ int s_cut;
    uint32_t prefix = 0;
    bool exact = false;
    for (int bit = 30; bit >= 0; --bit) {
        uint32_t c = prefix | (1u << bit);
        int cnt = 0;
#pragma unroll
        for (int i = 0; i < 16; ++i) cnt += (u[i] >= c) ? 1 : 0;
#pragma unroll
        for (int off = 32; off; off >>= 1) cnt += __shfl_xor(cnt, off);
        if ((t & 63) == 0) red[t >> 6] = cnt;
        __syncthreads();
        int total = red[0] + red[1] + red[2] + red[3];
        __syncthreads();
        if (total >= 64) prefix = c;
        if (total == 64) { exact = true; break; }
    }
    float* orow = out + (((size_t)row) << 12);
    if (exact) {
#pragma unroll
        for (int i = 0; i < 16; ++i) {
            int col = t + (i << 8);
            orow[col] = (u[i] >= prefix) ? v[i] : 0.f;
        }
        return;
    }
    const uint32_t T64 = prefix;
    int cg = 0;
#pragma unroll
    for (int i = 0; i < 16; ++i) cg += (u[i] > T64) ? 1 : 0;
#pragma unroll
    for (int off = 32; off; off >>= 1) cg += __shfl_xor(cg, off);
    if ((t & 63) == 0) red[t >> 6] = cg;
    __syncthreads();
    const int ngt = red[0] + red[1] + red[2] + red[3];
    int cut = -1;
    if (T64 != 0u) {
        const int r = 64 - ngt;
        if (t < 64) bits[t] = 0ull;
        __syncthreads();
#pragma unroll
        for (int i = 0; i < 16; ++i) {
            if (u[i] == T64) {
                int col = t + (i << 8);
                atomicOr(&bits[col >> 6], 1ull << (col & 63));
            }
        }
        __syncthreads();
        if (t == 0) {
            int need = r, cs = FDIM - 1;
            for (int wd = 0; wd < 64; ++wd) {
                int pc = __popcll(bits[wd]);
                if (need <= pc) {
                    unsigned long long bb = bits[wd];
                    for (int q = 1; q < need; ++q) bb &= bb - 1;
                    cs = (wd << 6) + (__ffsll(bb) - 1);
                    break;
                }
                need -= pc;
            }
            s_cut = cs;
        }
        __syncthreads();
        cut = s_cut;
    }
#pragma unroll
    for (int i = 0; i < 16; ++i) {
        int col = t + (i << 8);
        bool keep = (u[i] > T64) || (T64 != 0u && u[i] == T64 && col <= cut);
        orow[col] = keep ? v[i] : 0.f;
    }
}

extern "C" void kernel_launch(void* const* d_in, const int* in_sizes, int n_in,
                              void* d_out, int out_size, void* d_ws, size_t ws_size,
                              hipStream_t stream) {
    const float* zL      = (const float*)d_in[0];
    const float* gamma_l = (const float*)d_in[5];
    const float* beta_l  = (const float*)d_in[6];
    const float* gamma_d = (const float*)d_in[11];
    const float* beta_d  = (const float*)d_in[12];
    const float* dict_e  = (const float*)d_in[13];
    const float* bias_pre= (const float*)d_in[14];
    const float* bias_enc= (const float*)d_in[15];
    const float* qt      = (const float*)d_in[16];
    const float* wproj[8] = { (const float*)d_in[1], (const float*)d_in[2],
                              (const float*)d_in[3], (const float*)d_in[4],
                              (const float*)d_in[7], (const float*)d_in[8],
                              (const float*)d_in[9], (const float*)d_in[10] };
    // order: wq_l, wk_l, wv_l, wo_l, wq_d, wk_d, wv_d, wo_d

    float* out_z  = (float*)d_out;
    float* out_xp = out_z + (size_t)NTOK * FDIM;

    const size_t NHf = (size_t)NTOK * HDIM;
    float* B0 = (float*)d_out;         // residual X (z_n region)
    float* B1 = B0 + NHf;              // fused QKV [16384][1536] (3*NHf)

    float* wsf    = (float*)d_ws;
    float* logits = wsf + 64;

    const size_t dictE = (size_t)FDIM * HDIM;   // 2.1M
    const size_t WE    = (size_t)HDIM * HDIM;   // 262144

    int crows = 2048;                  // L3-resident logits chunk (33.5 MB)
    const size_t fixedB = 64 * sizeof(float)
                        + (2 * dictE + 16 * WE + 2 * NHf) * sizeof(_Float16);
    while (crows > 128 && fixedB + (size_t)crows * FDIM * sizeof(float) > ws_size)
        crows >>= 1;

    _Float16* dh  = (_Float16*)(logits + (size_t)crows * FDIM);
    _Float16* dl  = dh + dictE;
    _Float16* wsp = dh + 2 * dictE;    // 16 WE: per layer [qkv_h 3WE][qkv_l 3WE][wo_h][wo_l]
    _Float16* xh  = wsp + 16 * WE;
    _Float16* xl  = xh + NHf;
    // layer L
    _Float16* qkvh_l = wsp;
    _Float16* qkvl_l = wsp + 3 * WE;
    _Float16* woh_l  = wsp + 6 * WE;
    _Float16* wol_l  = wsp + 7 * WE;
    // layer D
    _Float16* qkvh_d = wsp + 8 * WE;
    _Float16* qkvl_d = wsp + 11 * WE;
    _Float16* woh_d  = wsp + 14 * WE;
    _Float16* wol_d  = wsp + 15 * WE;

    const dim3 blk256(256), blk128(128), blk512(512);
    const dim3 gElem(4096);                       // NTOK*512/8/256
    const dim3 gW(WE / 8 / 256);
    const dim3 gQKV(QKVD / 64, NTOK / 128);       // (24, 128)
    const dim3 gWo(HDIM / 64, NTOK / 128);        // (8, 128)

    // weight splits: QKV stacked contiguously per layer
    split2_k<<<gW, blk256, 0, stream>>>(wproj[0], qkvh_l,          qkvl_l);
    split2_k<<<gW, blk256, 0, stream>>>(wproj[1], qkvh_l + WE,     qkvl_l + WE);
    split2_k<<<gW, blk256, 0, stream>>>(wproj[2], qkvh_l + 2 * WE, qkvl_l + 2 * WE);
    split2_k<<<gW, blk256, 0, stream>>>(wproj[3], woh_l,           wol_l);
    split2_k<<<gW, blk256, 0, stream>>>(wproj[4], qkvh_d,          qkvl_d);
    split2_k<<<gW, blk256, 0, stream>>>(wproj[5], qkvh_d + WE,     qkvl_d + WE);
    split2_k<<<gW, blk256, 0, stream>>>(wproj[6], qkvh_d + 2 * WE, qkvl_d + 2 * WE);
    split2_k<<<gW, blk256, 0, stream>>>(wproj[7], woh_d,           wol_d);
    split2_k<<<dim3(dictE / 8 / 256), blk256, 0, stream>>>(dict_e, dh, dl);

    build_x_k<<<gElem, blk256, 0, stream>>>(zL, qt, B0);

    // ---- layer attention block ----
    ln_split_k<<<dim3(NTOK / 4), blk256, 0, stream>>>(B0, gamma_l, beta_l, xh, xl);
    gemm_f16_k<false, false><<<gQKV, blk256, 0, stream>>>(xh, xl, qkvh_l, qkvl_l, nullptr, B1, QKVD);
    attn_l_k<<<dim3(128, NHEAD), blk512, 0, stream>>>(B1, xh, xl);
    gemm_f16_k<true, false><<<gWo, blk256, 0, stream>>>(xh, xl, woh_l, wol_l, nullptr, B0, HDIM);

    // ---- depth attention block ----
    ln_split_k<<<dim3(NTOK / 4), blk256, 0, stream>>>(B0, gamma_d, beta_d, xh, xl);
    gemm_f16_k<false, false><<<gQKV, blk256, 0, stream>>>(xh, xl, qkvh_d, qkvl_d, nullptr, B1, QKVD);
    attn_d_k<<<dim3(1024), blk128, 0, stream>>>(B1, xh, xl);
    gemm_f16_k<true, false><<<gWo, blk256, 0, stream>>>(xh, xl, woh_d, wol_d, nullptr, B0, HDIM);

    // ---- x_prior out + x_src split (B0/B1 freed for z_n writes) ----
    xprior_xsrc_k<<<gElem, blk256, 0, stream>>>(zL, bias_pre, B0, out_xp, xh, xl);

    const dim3 gDict(FDIM / 64, crows / 128);
    for (int c0 = 0; c0 < NTOK; c0 += crows) {
        gemm_f16_k<false, true><<<gDict, blk256, 0, stream>>>(
            xh + (size_t)c0 * HDIM, xl + (size_t)c0 * HDIM,
            dh, dl, bias_enc, logits, FDIM);
        topk_k<<<dim3(crows), blk256, 0, stream>>>(logits, out_z + (size_t)c0 * FDIM);
    }
}

// Round 16
// 1173.354 us; speedup vs baseline: 1.0162x; 1.0162x over previous
//
#include <hip/hip_runtime.h>
#include <stdint.h>

#define NTOK 16384        // B*D*L = 8*16*128
#define HDIM 512
#define FDIM 4096
#define NHEAD 8
#define QKVD 1536         // fused QKV row width
#define L2E 1.44269504f   // log2(e)

typedef __attribute__((ext_vector_type(8))) _Float16 f16x8;
typedef __attribute__((ext_vector_type(16))) float f32x16;
#define LOSCALE 4096.0f
#define LOINV   (1.0f / 4096.0f)

static __device__ __forceinline__ void ld8f(const float* p, float* v) {
    *(float4*)&v[0] = *(const float4*)p;
    *(float4*)&v[4] = *(const float4*)(p + 4);
}
static __device__ __forceinline__ void st8f(float* p, const float* v) {
    *(float4*)p       = *(const float4*)&v[0];
    *(float4*)(p + 4) = *(const float4*)&v[4];
}

// ---- x0 = concat(query_token, zL[:, :-1]) -> f32 ----
__global__ __launch_bounds__(256) void build_x_k(const float* __restrict__ zL,
                                                 const float* __restrict__ qt,
                                                 float* __restrict__ X) {
    int idx = blockIdx.x * 256 + threadIdx.x;
    int n = idx >> 6;
    int h = (idx & 63) << 3;
    int d = (n >> 7) & 15;
    const float* src = d ? (zL + (((size_t)(n - 128)) << 9) + h) : (qt + h);
    float v[8];
    ld8f(src, v);
    st8f(X + (((size_t)n) << 9) + h, v);
}

// ---- fused LN stats + LN + fp16 2-way split (one wave per row) ----
__global__ __launch_bounds__(256) void ln_split_k(const float* __restrict__ X,
                                                  const float* __restrict__ gamma,
                                                  const float* __restrict__ beta,
                                                  _Float16* __restrict__ ph,
                                                  _Float16* __restrict__ pl) {
    int row = blockIdx.x * 4 + (threadIdx.x >> 6);
    int lane = threadIdx.x & 63;
    int h = lane << 3;
    const float* xr = X + (((size_t)row) << 9) + h;
    float v[8];
    ld8f(xr, v);
    float s = 0.f;
#pragma unroll
    for (int i = 0; i < 8; ++i) s += v[i];
#pragma unroll
    for (int off = 32; off; off >>= 1) s += __shfl_xor(s, off);
    float m = s * (1.0f / 512.0f);
    float q = 0.f;
#pragma unroll
    for (int i = 0; i < 8; ++i) { float d = v[i] - m; q += d * d; }
#pragma unroll
    for (int off = 32; off; off >>= 1) q += __shfl_xor(q, off);
    float rs = 1.0f / sqrtf(q * (1.0f / 512.0f) + 1e-5f);
    float gv[8], be[8];
    ld8f(gamma + h, gv);
    ld8f(beta + h, be);
    _Float16 h8[8], l8[8];
#pragma unroll
    for (int i = 0; i < 8; ++i) {
        float y = (v[i] - m) * rs * gv[i] + be[i];
        _Float16 hh = (_Float16)y;
        h8[i] = hh;
        l8[i] = (_Float16)((y - (float)hh) * LOSCALE);
    }
    size_t off = (((size_t)row) << 9) + h;
    *(int4*)(ph + off) = *(int4*)h8;
    *(int4*)(pl + off) = *(int4*)l8;
}

// ---- non-causal attention over L; strided-d lanes (bank-conflict-free) ----
// Lane q = t&3 owns dims {q+4i}. LDS reads hit 4 distinct banks (4i+q),
// 16-lane broadcast groups -> conflict-free (round-15 counter: 2-way on
// every read with contiguous 16-blocks).
__global__ __launch_bounds__(512) void attn_l_k(const float* __restrict__ QKV,
                                                _Float16* __restrict__ xh,
                                                _Float16* __restrict__ xl) {
    __shared__ float ks[128][64];
    __shared__ float vs[128][64];
    const int seq = blockIdx.x, head = blockIdx.y;
    const int t = threadIdx.x;
    const size_t tok0 = (size_t)seq << 7;
    const int ho = head << 6;
#pragma unroll
    for (int i = 0; i < 4; ++i) {
        int slot = t + (i << 9);
        int row = slot >> 4;
        int c4 = (slot & 15) << 2;
        size_t g = (tok0 + row) * QKVD + ho + c4;
        *(float4*)&ks[row][c4] = *(const float4*)(QKV + g + 512);
        *(float4*)&vs[row][c4] = *(const float4*)(QKV + g + 1024);
    }
    __syncthreads();
    const int r = t >> 2;
    const int q = t & 3;              // strided-d lane: dims q, q+4, ..., q+60
    const float* qp = QKV + (tok0 + r) * QKVD + ho;
    float qr[16];
#pragma unroll
    for (int i = 0; i < 16; ++i) qr[i] = qp[(i << 2) + q];
    float o[16];
#pragma unroll
    for (int d = 0; d < 16; ++d) o[d] = 0.f;
    float m = -1e30f, l = 0.f;
    for (int j = 0; j < 128; ++j) {
        const float* kp = &ks[j][q];
        float s0 = 0.f, s1 = 0.f, s2 = 0.f, s3 = 0.f;
#pragma unroll
        for (int i = 0; i < 16; i += 4) {
            s0 = fmaf(qr[i + 0], kp[(i + 0) << 2], s0);
            s1 = fmaf(qr[i + 1], kp[(i + 1) << 2], s1);
            s2 = fmaf(qr[i + 2], kp[(i + 2) << 2], s2);
            s3 = fmaf(qr[i + 3], kp[(i + 3) << 2], s3);
        }
        float sp = (s0 + s1) + (s2 + s3);
        sp += __shfl_xor(sp, 1);
        sp += __shfl_xor(sp, 2);
        float s = sp * 0.125f;
        if (s > m) {
            float c = exp2f((m - s) * L2E);
#pragma unroll
            for (int d = 0; d < 16; ++d) o[d] *= c;
            l *= c;
            m = s;
        }
        float w = exp2f((s - m) * L2E);
        l += w;
        const float* vp = &vs[j][q];
#pragma unroll
        for (int i = 0; i < 16; ++i) o[i] = fmaf(w, vp[i << 2], o[i]);
    }
    float inv = 1.0f / l;
    size_t eo = ((tok0 + r) << 9) + ho + q;
#pragma unroll
    for (int i = 0; i < 16; ++i) {
        float y = o[i] * inv;
        _Float16 hh = (_Float16)y;
        xh[eo + (i << 2)] = hh;
        xl[eo + (i << 2)] = (_Float16)((y - (float)hh) * LOSCALE);
    }
}

// ---- causal attention over D; per-head col rotation (bank-conflict-free) ---
// col 64h+d stored at 64h+((d+4h)&63): head-segments start at distinct banks.
__global__ __launch_bounds__(128) void attn_d_k(const float* __restrict__ QKV,
                                                _Float16* __restrict__ xh,
                                                _Float16* __restrict__ xl) {
    __shared__ float ks[16][512];
    __shared__ float vs[16][512];
    const int bl = blockIdx.x;
    const int b = bl >> 7, l = bl & 127;
    const int t = threadIdx.x;
    const size_t tok0 = (size_t)b * 2048 + l;
#pragma unroll
    for (int i = 0; i < 16; ++i) {
        int c4 = t << 2;
        int hc = c4 >> 6;
        int p  = (c4 & ~63) | ((c4 + (hc << 2)) & 63);   // rotated position
        size_t g = (tok0 + (size_t)i * 128) * QKVD + c4;
        *(float4*)&ks[i][p] = *(const float4*)(QKV + g + 512);
        *(float4*)&vs[i][p] = *(const float4*)(QKV + g + 1024);
    }
    __syncthreads();
    const int head = t >> 4, dr = t & 15;
    const int ho = head << 6;
    const int rot = head << 2;
    float qr[64];
    const float* qp = QKV + (tok0 + (size_t)dr * 128) * QKVD + ho;
#pragma unroll
    for (int i = 0; i < 16; ++i) *(float4*)&qr[i << 2] = *(const float4*)(qp + (i << 2));
    float s[16];
    float m = -1e30f;
#pragma unroll
    for (int j = 0; j < 16; ++j) {
        float s0 = 0.f, s1 = 0.f, s2 = 0.f, s3 = 0.f;
#pragma unroll
        for (int d = 0; d < 64; d += 4) {
            s0 = fmaf(qr[d + 0], ks[j][ho + ((d + 0 + rot) & 63)], s0);
            s1 = fmaf(qr[d + 1], ks[j][ho + ((d + 1 + rot) & 63)], s1);
            s2 = fmaf(qr[d + 2], ks[j][ho + ((d + 2 + rot) & 63)], s2);
            s3 = fmaf(qr[d + 3], ks[j][ho + ((d + 3 + rot) & 63)], s3);
        }
        float sv = ((s0 + s1) + (s2 + s3)) * 0.125f;
        s[j] = (j <= dr) ? sv : -1e30f;
        m = fmaxf(m, s[j]);
    }
    float lsum = 0.f;
#pragma unroll
    for (int j = 0; j < 16; ++j) {
        float w = (j <= dr) ? exp2f((s[j] - m) * L2E) : 0.f;
        s[j] = w;
        lsum += w;
    }
    float inv = 1.0f / lsum;
    float o[64];
#pragma unroll
    for (int d = 0; d < 64; ++d) o[d] = 0.f;
#pragma unroll
    for (int j = 0; j < 16; ++j) {
        float w = s[j];
#pragma unroll
        for (int d = 0; d < 64; ++d) o[d] = fmaf(w, vs[j][ho + ((d + rot) & 63)], o[d]);
    }
    size_t eo = ((tok0 + (size_t)dr * 128) << 9) + ho;
#pragma unroll
    for (int i = 0; i < 8; ++i) {
        _Float16 h8[8], l8[8];
#pragma unroll
        for (int j = 0; j < 8; ++j) {
            float y = o[i * 8 + j] * inv;
            _Float16 hh = (_Float16)y;
            h8[j] = hh;
            l8[j] = (_Float16)((y - (float)hh) * LOSCALE);
        }
        *(int4*)(xh + eo + (i << 3)) = *(int4*)h8;
        *(int4*)(xl + eo + (i << 3)) = *(int4*)l8;
    }
}

// ---- fused: out_xp = x; split(zL - x - bias_pre) -> xh/xl ----
__global__ __launch_bounds__(256) void xprior_xsrc_k(const float* __restrict__ zL,
                                                     const float* __restrict__ bias_pre,
                                                     const float* __restrict__ X,
                                                     float* __restrict__ out_xp,
                                                     _Float16* __restrict__ xh,
                                                     _Float16* __restrict__ xl) {
    int idx = blockIdx.x * 256 + threadIdx.x;
    int h = (idx & 63) << 3;
    size_t off = ((size_t)idx) << 3;
    float z[8], p[8], x[8];
    ld8f(zL + off, z);
    ld8f(bias_pre + h, p);
    ld8f(X + off, x);
    st8f(out_xp + off, x);
    _Float16 h8[8], l8[8];
#pragma unroll
    for (int i = 0; i < 8; ++i) {
        float y = z[i] - x[i] - p[i];
        _Float16 hh = (_Float16)y;
        h8[i] = hh;
        l8[i] = (_Float16)((y - (float)hh) * LOSCALE);
    }
    *(int4*)(xh + off) = *(int4*)h8;
    *(int4*)(xl + off) = *(int4*)l8;
}

// ---- 2-way fp16 scaled split: x = h + l*2^-12 ----
__global__ __launch_bounds__(256) void split2_k(const float* __restrict__ in,
                                                _Float16* __restrict__ ph,
                                                _Float16* __restrict__ pl) {
    int idx = blockIdx.x * 256 + threadIdx.x;
    float v[8];
    ld8f(in + (((size_t)idx) << 3), v);
    _Float16 h8[8], l8[8];
#pragma unroll
    for (int i = 0; i < 8; ++i) {
        _Float16 h = (_Float16)v[i];
        float r = v[i] - (float)h;          // exact
        h8[i] = h;
        l8[i] = (_Float16)(r * LOSCALE);
    }
    *(int4*)(ph + (((size_t)idx) << 3)) = *(int4*)h8;
    *(int4*)(pl + (((size_t)idx) << 3)) = *(int4*)l8;
}

// ---- 3-pass split-fp16 MFMA NT GEMM, 32x32x16, 128x64 tile, 2-phase dbuf ---
// (unchanged — validated at absmax floor across rounds 11-15)
#define LDT 34
template<bool ADD_C, bool BIAS>
__global__ __launch_bounds__(256) void gemm_f16_k(
        const _Float16* __restrict__ Xh, const _Float16* __restrict__ Xl,
        const _Float16* __restrict__ Wh, const _Float16* __restrict__ Wl,
        const float* __restrict__ bias, float* __restrict__ Cout, int ldc) {
    __shared__ _Float16 Ah[2][128][LDT], Al[2][128][LDT];
    __shared__ _Float16 Bh[2][64][LDT],  Bl[2][64][LDT];
    const int tid = threadIdx.x;
    const int bm = blockIdx.y << 7;
    const int bn = blockIdx.x << 6;
    const int w = tid >> 6, lane = tid & 63;
    const int wr = w >> 1, wc = w & 1;
    const int l31 = lane & 31, hh = lane >> 5;
    const int ar0 = tid >> 2, akg = (tid & 3) << 3;
    const int ar1 = ar0 + 64;
    const _Float16* pXh0 = Xh + (size_t)(bm + ar0) * HDIM + akg;
    const _Float16* pXl0 = Xl + (size_t)(bm + ar0) * HDIM + akg;
    const _Float16* pXh1 = Xh + (size_t)(bm + ar1) * HDIM + akg;
    const _Float16* pXl1 = Xl + (size_t)(bm + ar1) * HDIM + akg;
    const _Float16* pWh  = Wh + (size_t)(bn + ar0) * HDIM + akg;
    const _Float16* pWl  = Wl + (size_t)(bn + ar0) * HDIM + akg;

    f32x16 acc1[2], acc2[2];
#pragma unroll
    for (int i = 0; i < 2; ++i)
#pragma unroll
        for (int r = 0; r < 16; ++r) { acc1[i][r] = 0.f; acc2[i][r] = 0.f; }

    int4 ra0h, ra0l, ra1h, ra1l, rbh, rbl;
    auto LOADR = [&](int k0) {
        ra0h = *(const int4*)(pXh0 + k0);
        ra0l = *(const int4*)(pXl0 + k0);
        ra1h = *(const int4*)(pXh1 + k0);
        ra1l = *(const int4*)(pXl1 + k0);
        rbh  = *(const int4*)(pWh + k0);
        rbl  = *(const int4*)(pWl + k0);
    };
    auto STORE = [&](int buf) {
        *(int4*)&Ah[buf][ar0][akg] = ra0h;
        *(int4*)&Al[buf][ar0][akg] = ra0l;
        *(int4*)&Ah[buf][ar1][akg] = ra1h;
        *(int4*)&Al[buf][ar1][akg] = ra1l;
        *(int4*)&Bh[buf][ar0][akg] = rbh;
        *(int4*)&Bl[buf][ar0][akg] = rbl;
    };

    LOADR(0);
    STORE(0);
    int cur = 0;
    for (int it = 0; it < 16; ++it) {
        if (it < 15) LOADR((it + 1) << 5);
        __syncthreads();
#pragma unroll
        for (int kh = 0; kh < 2; ++kh) {
            const int ko = (kh << 4) + (hh << 3);
            f16x8 fah[2], fal[2];
#pragma unroll
            for (int mf = 0; mf < 2; ++mf) {
                int ar = (wr << 6) + (mf << 5) + l31;
                fah[mf] = *(const f16x8*)&Ah[cur][ar][ko];
                fal[mf] = *(const f16x8*)&Al[cur][ar][ko];
            }
            int bc_ = (wc << 5) + l31;
            f16x8 bh = *(const f16x8*)&Bh[cur][bc_][ko];
            f16x8 bl = *(const f16x8*)&Bl[cur][bc_][ko];
#pragma unroll
            for (int mf = 0; mf < 2; ++mf) {
                acc1[mf] = __builtin_amdgcn_mfma_f32_32x32x16_f16(fah[mf], bh, acc1[mf], 0, 0, 0);
                acc2[mf] = __builtin_amdgcn_mfma_f32_32x32x16_f16(fah[mf], bl, acc2[mf], 0, 0, 0);
                acc2[mf] = __builtin_amdgcn_mfma_f32_32x32x16_f16(fal[mf], bh, acc2[mf], 0, 0, 0);
            }
        }
        if (it < 15) { STORE(cur ^ 1); cur ^= 1; }
    }
    const int col = bn + (wc << 5) + l31;
    const float badd = BIAS ? bias[col] : 0.f;
#pragma unroll
    for (int mf = 0; mf < 2; ++mf) {
#pragma unroll
        for (int r = 0; r < 16; ++r) {
            int row = bm + (wr << 6) + (mf << 5) + (r & 3) + ((r >> 2) << 3) + (hh << 2);
            float* cp = Cout + (size_t)row * ldc + col;
            float val = acc1[mf][r] + acc2[mf][r] * LOINV + badd;
            if (ADD_C) val += *cp;
            *cp = val;
        }
    }
}

// ---- per-row top-64: relu + exact radix select (early-exit) + scatter ----
__global__ __launch_bounds__(256) void topk_k(const float* __restrict__ logits,
                                              float* __restrict__ out) {
    const int row = blockIdx.x;
    const float* lr = logits + (((size_t)row) << 12);
    const int t = threadIdx.x;
    float v[16]; uint32_t u[16];
#pragma unroll
    for (int i = 0; i < 16; ++i) {
        float x = fmaxf(lr[t + (i << 8)], 0.f);
        v[i] = x;
        u[i] = __float_as_uint(x);
    }
    __shared__ int red[4];
    __shared__ unsigned long long bits[64];
    __shared__ int s_cut;
    uint32_t prefix = 0;
    bool exact = false;
    for (int bit = 30; bit >= 0; --bit) {
        uint32_t c = prefix | (1u << bit);
        int cnt = 0;
#pragma unroll
        for (int i = 0; i < 16; ++i) cnt += (u[i] >= c) ? 1 : 0;
#pragma unroll
        for (int off = 32; off; off >>= 1) cnt += __shfl_xor(cnt, off);
        if ((t & 63) == 0) red[t >> 6] = cnt;
        __syncthreads();
        int total = red[0] + red[1] + red[2] + red[3];
        __syncthreads();
        if (total >= 64) prefix = c;
        if (total == 64) { exact = true; break; }
    }
    float* orow = out + (((size_t)row) << 12);
    if (exact) {
#pragma unroll
        for (int i = 0; i < 16; ++i) {
            int col = t + (i << 8);
            orow[col] = (u[i] >= prefix) ? v[i] : 0.f;
        }
        return;
    }
    const uint32_t T64 = prefix;
    int cg = 0;
#pragma unroll
    for (int i = 0; i < 16; ++i) cg += (u[i] > T64) ? 1 : 0;
#pragma unroll
    for (int off = 32; off; off >>= 1) cg += __shfl_xor(cg, off);
    if ((t & 63) == 0) red[t >> 6] = cg;
    __syncthreads();
    const int ngt = red[0] + red[1] + red[2] + red[3];
    int cut = -1;
    if (T64 != 0u) {
        const int r = 64 - ngt;
        if (t < 64) bits[t] = 0ull;
        __syncthreads();
#pragma unroll
        for (int i = 0; i < 16; ++i) {
            if (u[i] == T64) {
                int col = t + (i << 8);
                atomicOr(&bits[col >> 6], 1ull << (col & 63));
            }
        }
        __syncthreads();
        if (t == 0) {
            int need = r, cs = FDIM - 1;
            for (int wd = 0; wd < 64; ++wd) {
                int pc = __popcll(bits[wd]);
                if (need <= pc) {
                    unsigned long long bb = bits[wd];
                    for (int q = 1; q < need; ++q) bb &= bb - 1;
                    cs = (wd << 6) + (__ffsll(bb) - 1);
                    break;
                }
                need -= pc;
            }
            s_cut = cs;
        }
        __syncthreads();
        cut = s_cut;
    }
#pragma unroll
    for (int i = 0; i < 16; ++i) {
        int col = t + (i << 8);
        bool keep = (u[i] > T64) || (T64 != 0u && u[i] == T64 && col <= cut);
        orow[col] = keep ? v[i] : 0.f;
    }
}

extern "C" void kernel_launch(void* const* d_in, const int* in_sizes, int n_in,
                              void* d_out, int out_size, void* d_ws, size_t ws_size,
                              hipStream_t stream) {
    const float* zL      = (const float*)d_in[0];
    const float* gamma_l = (const float*)d_in[5];
    const float* beta_l  = (const float*)d_in[6];
    const float* gamma_d = (const float*)d_in[11];
    const float* beta_d  = (const float*)d_in[12];
    const float* dict_e  = (const float*)d_in[13];
    const float* bias_pre= (const float*)d_in[14];
    const float* bias_enc= (const float*)d_in[15];
    const float* qt      = (const float*)d_in[16];
    const float* wproj[8] = { (const float*)d_in[1], (const float*)d_in[2],
                              (const float*)d_in[3], (const float*)d_in[4],
                              (const float*)d_in[7], (const float*)d_in[8],
                              (const float*)d_in[9], (const float*)d_in[10] };

    float* out_z  = (float*)d_out;
    float* out_xp = out_z + (size_t)NTOK * FDIM;

    const size_t NHf = (size_t)NTOK * HDIM;
    float* B0 = (float*)d_out;         // residual X (z_n region)
    float* B1 = B0 + NHf;              // fused QKV [16384][1536]

    float* wsf    = (float*)d_ws;
    float* logits = wsf + 64;

    const size_t dictE = (size_t)FDIM * HDIM;
    const size_t WE    = (size_t)HDIM * HDIM;

    int crows = 2048;                  // L3-resident logits chunk
    const size_t fixedB = 64 * sizeof(float)
                        + (2 * dictE + 16 * WE + 2 * NHf) * sizeof(_Float16);
    while (crows > 128 && fixedB + (size_t)crows * FDIM * sizeof(float) > ws_size)
        crows >>= 1;

    _Float16* dh  = (_Float16*)(logits + (size_t)crows * FDIM);
    _Float16* dl  = dh + dictE;
    _Float16* wsp = dh + 2 * dictE;
    _Float16* xh  = wsp + 16 * WE;
    _Float16* xl  = xh + NHf;
    _Float16* qkvh_l = wsp;
    _Float16* qkvl_l = wsp + 3 * WE;
    _Float16* woh_l  = wsp + 6 * WE;
    _Float16* wol_l  = wsp + 7 * WE;
    _Float16* qkvh_d = wsp + 8 * WE;
    _Float16* qkvl_d = wsp + 11 * WE;
    _Float16* woh_d  = wsp + 14 * WE;
    _Float16* wol_d  = wsp + 15 * WE;

    const dim3 blk256(256), blk128(128), blk512(512);
    const dim3 gElem(4096);
    const dim3 gW(WE / 8 / 256);
    const dim3 gQKV(QKVD / 64, NTOK / 128);
    const dim3 gWo(HDIM / 64, NTOK / 128);

    split2_k<<<gW, blk256, 0, stream>>>(wproj[0], qkvh_l,          qkvl_l);
    split2_k<<<gW, blk256, 0, stream>>>(wproj[1], qkvh_l + WE,     qkvl_l + WE);
    split2_k<<<gW, blk256, 0, stream>>>(wproj[2], qkvh_l + 2 * WE, qkvl_l + 2 * WE);
    split2_k<<<gW, blk256, 0, stream>>>(wproj[3], woh_l,           wol_l);
    split2_k<<<gW, blk256, 0, stream>>>(wproj[4], qkvh_d,          qkvl_d);
    split2_k<<<gW, blk256, 0, stream>>>(wproj[5], qkvh_d + WE,     qkvl_d + WE);
    split2_k<<<gW, blk256, 0, stream>>>(wproj[6], qkvh_d + 2 * WE, qkvl_d + 2 * WE);
    split2_k<<<gW, blk256, 0, stream>>>(wproj[7], woh_d,           wol_d);
    split2_k<<<dim3(dictE / 8 / 256), blk256, 0, stream>>>(dict_e, dh, dl);

    build_x_k<<<gElem, blk256, 0, stream>>>(zL, qt, B0);

    // ---- layer attention block ----
    ln_split_k<<<dim3(NTOK / 4), blk256, 0, stream>>>(B0, gamma_l, beta_l, xh, xl);
    gemm_f16_k<false, false><<<gQKV, blk256, 0, stream>>>(xh, xl, qkvh_l, qkvl_l, nullptr, B1, QKVD);
    attn_l_k<<<dim3(128, NHEAD), blk512, 0, stream>>>(B1, xh, xl);
    gemm_f16_k<true, false><<<gWo, blk256, 0, stream>>>(xh, xl, woh_l, wol_l, nullptr, B0, HDIM);

    // ---- depth attention block ----
    ln_split_k<<<dim3(NTOK / 4), blk256, 0, stream>>>(B0, gamma_d, beta_d, xh, xl);
    gemm_f16_k<false, false><<<gQKV, blk256, 0, stream>>>(xh, xl, qkvh_d, qkvl_d, nullptr, B1, QKVD);
    attn_d_k<<<dim3(1024), blk128, 0, stream>>>(B1, xh, xl);
    gemm_f16_k<true, false><<<gWo, blk256, 0, stream>>>(xh, xl, woh_d, wol_d, nullptr, B0, HDIM);

    // ---- x_prior out + x_src split ----
    xprior_xsrc_k<<<gElem, blk256, 0, stream>>>(zL, bias_pre, B0, out_xp, xh, xl);

    const dim3 gDict(FDIM / 64, crows / 128);
    for (int c0 = 0; c0 < NTOK; c0 += crows) {
        gemm_f16_k<false, true><<<gDict, blk256, 0, stream>>>(
            xh + (size_t)c0 * HDIM, xl + (size_t)c0 * HDIM,
            dh, dl, bias_enc, logits, FDIM);
        topk_k<<<dim3(crows), blk256, 0, stream>>>(logits, out_z + (size_t)c0 * FDIM);
    }
}

// Round 17
// 1166.149 us; speedup vs baseline: 1.0225x; 1.0062x over previous
//
#include <hip/hip_runtime.h>
#include <stdint.h>

#define NTOK 16384        // B*D*L = 8*16*128
#define HDIM 512
#define FDIM 4096
#define NHEAD 8
#define QKVD 1536         // fused QKV row width
#define L2E 1.44269504f   // log2(e)

typedef __attribute__((ext_vector_type(8))) _Float16 f16x8;
typedef __attribute__((ext_vector_type(16))) float f32x16;
#define LOSCALE 4096.0f
#define LOINV   (1.0f / 4096.0f)

static __device__ __forceinline__ void ld8f(const float* p, float* v) {
    *(float4*)&v[0] = *(const float4*)p;
    *(float4*)&v[4] = *(const float4*)(p + 4);
}
static __device__ __forceinline__ void st8f(float* p, const float* v) {
    *(float4*)p       = *(const float4*)&v[0];
    *(float4*)(p + 4) = *(const float4*)&v[4];
}

// ---- x0 = concat(query_token, zL[:, :-1]) -> f32 ----
__global__ __launch_bounds__(256) void build_x_k(const float* __restrict__ zL,
                                                 const float* __restrict__ qt,
                                                 float* __restrict__ X) {
    int idx = blockIdx.x * 256 + threadIdx.x;
    int n = idx >> 6;
    int h = (idx & 63) << 3;
    int d = (n >> 7) & 15;
    const float* src = d ? (zL + (((size_t)(n - 128)) << 9) + h) : (qt + h);
    float v[8];
    ld8f(src, v);
    st8f(X + (((size_t)n) << 9) + h, v);
}

// ---- fused LN stats + LN + fp16 2-way split (one wave per row) ----
__global__ __launch_bounds__(256) void ln_split_k(const float* __restrict__ X,
                                                  const float* __restrict__ gamma,
                                                  const float* __restrict__ beta,
                                                  _Float16* __restrict__ ph,
                                                  _Float16* __restrict__ pl) {
    int row = blockIdx.x * 4 + (threadIdx.x >> 6);
    int lane = threadIdx.x & 63;
    int h = lane << 3;
    const float* xr = X + (((size_t)row) << 9) + h;
    float v[8];
    ld8f(xr, v);
    float s = 0.f;
#pragma unroll
    for (int i = 0; i < 8; ++i) s += v[i];
#pragma unroll
    for (int off = 32; off; off >>= 1) s += __shfl_xor(s, off);
    float m = s * (1.0f / 512.0f);
    float q = 0.f;
#pragma unroll
    for (int i = 0; i < 8; ++i) { float d = v[i] - m; q += d * d; }
#pragma unroll
    for (int off = 32; off; off >>= 1) q += __shfl_xor(q, off);
    float rs = 1.0f / sqrtf(q * (1.0f / 512.0f) + 1e-5f);
    float gv[8], be[8];
    ld8f(gamma + h, gv);
    ld8f(beta + h, be);
    _Float16 h8[8], l8[8];
#pragma unroll
    for (int i = 0; i < 8; ++i) {
        float y = (v[i] - m) * rs * gv[i] + be[i];
        _Float16 hh = (_Float16)y;
        h8[i] = hh;
        l8[i] = (_Float16)((y - (float)hh) * LOSCALE);
    }
    size_t off = (((size_t)row) << 9) + h;
    *(int4*)(ph + off) = *(int4*)h8;
    *(int4*)(pl + off) = *(int4*)l8;
}

// ---- non-causal attention over L; strided-d lanes; j-tiled (32KB LDS) ----
// K/V staged in two 64-row tiles so 4 blocks/CU fit (was 2 at 64KB).
__global__ __launch_bounds__(512) void attn_l_k(const float* __restrict__ QKV,
                                                _Float16* __restrict__ xh,
                                                _Float16* __restrict__ xl) {
    __shared__ float ks[64][64];
    __shared__ float vs[64][64];
    const int seq = blockIdx.x, head = blockIdx.y;
    const int t = threadIdx.x;
    const size_t tok0 = (size_t)seq << 7;
    const int ho = head << 6;
    const int r = t >> 2;
    const int q = t & 3;              // strided-d lane: dims q, q+4, ..., q+60
    const float* qp = QKV + (tok0 + r) * QKVD + ho;
    float qr[16];
#pragma unroll
    for (int i = 0; i < 16; ++i) qr[i] = qp[(i << 2) + q];
    float o[16];
#pragma unroll
    for (int d = 0; d < 16; ++d) o[d] = 0.f;
    float m = -1e30f, l = 0.f;
    for (int half = 0; half < 2; ++half) {
        const int j0 = half << 6;
        __syncthreads();              // prior tile fully consumed
#pragma unroll
        for (int i = 0; i < 2; ++i) {
            int slot = t + (i << 9);
            int row = slot >> 4;
            int c4 = (slot & 15) << 2;
            size_t g = (tok0 + j0 + row) * QKVD + ho + c4;
            *(float4*)&ks[row][c4] = *(const float4*)(QKV + g + 512);
            *(float4*)&vs[row][c4] = *(const float4*)(QKV + g + 1024);
        }
        __syncthreads();
        for (int j = 0; j < 64; ++j) {
            const float* kp = &ks[j][q];
            float s0 = 0.f, s1 = 0.f, s2 = 0.f, s3 = 0.f;
#pragma unroll
            for (int i = 0; i < 16; i += 4) {
                s0 = fmaf(qr[i + 0], kp[(i + 0) << 2], s0);
                s1 = fmaf(qr[i + 1], kp[(i + 1) << 2], s1);
                s2 = fmaf(qr[i + 2], kp[(i + 2) << 2], s2);
                s3 = fmaf(qr[i + 3], kp[(i + 3) << 2], s3);
            }
            float sp = (s0 + s1) + (s2 + s3);
            sp += __shfl_xor(sp, 1);
            sp += __shfl_xor(sp, 2);
            float s = sp * 0.125f;
            if (s > m) {
                float c = exp2f((m - s) * L2E);
#pragma unroll
                for (int d = 0; d < 16; ++d) o[d] *= c;
                l *= c;
                m = s;
            }
            float w = exp2f((s - m) * L2E);
            l += w;
            const float* vp = &vs[j][q];
#pragma unroll
            for (int i = 0; i < 16; ++i) o[i] = fmaf(w, vp[i << 2], o[i]);
        }
    }
    float inv = 1.0f / l;
    size_t eo = ((tok0 + r) << 9) + ho + q;
#pragma unroll
    for (int i = 0; i < 16; ++i) {
        float y = o[i] * inv;
        _Float16 hh = (_Float16)y;
        xh[eo + (i << 2)] = hh;
        xl[eo + (i << 2)] = (_Float16)((y - (float)hh) * LOSCALE);
    }
}

// ---- causal attention over D; per-head col rotation (bank-conflict-free) ---
__global__ __launch_bounds__(128) void attn_d_k(const float* __restrict__ QKV,
                                                _Float16* __restrict__ xh,
                                                _Float16* __restrict__ xl) {
    __shared__ float ks[16][512];
    __shared__ float vs[16][512];
    const int bl = blockIdx.x;
    const int b = bl >> 7, l = bl & 127;
    const int t = threadIdx.x;
    const size_t tok0 = (size_t)b * 2048 + l;
#pragma unroll
    for (int i = 0; i < 16; ++i) {
        int c4 = t << 2;
        int hc = c4 >> 6;
        int p  = (c4 & ~63) | ((c4 + (hc << 2)) & 63);
        size_t g = (tok0 + (size_t)i * 128) * QKVD + c4;
        *(float4*)&ks[i][p] = *(const float4*)(QKV + g + 512);
        *(float4*)&vs[i][p] = *(const float4*)(QKV + g + 1024);
    }
    __syncthreads();
    const int head = t >> 4, dr = t & 15;
    const int ho = head << 6;
    const int rot = head << 2;
    float qr[64];
    const float* qp = QKV + (tok0 + (size_t)dr * 128) * QKVD + ho;
#pragma unroll
    for (int i = 0; i < 16; ++i) *(float4*)&qr[i << 2] = *(const float4*)(qp + (i << 2));
    float s[16];
    float m = -1e30f;
#pragma unroll
    for (int j = 0; j < 16; ++j) {
        float s0 = 0.f, s1 = 0.f, s2 = 0.f, s3 = 0.f;
#pragma unroll
        for (int d = 0; d < 64; d += 4) {
            s0 = fmaf(qr[d + 0], ks[j][ho + ((d + 0 + rot) & 63)], s0);
            s1 = fmaf(qr[d + 1], ks[j][ho + ((d + 1 + rot) & 63)], s1);
            s2 = fmaf(qr[d + 2], ks[j][ho + ((d + 2 + rot) & 63)], s2);
            s3 = fmaf(qr[d + 3], ks[j][ho + ((d + 3 + rot) & 63)], s3);
        }
        float sv = ((s0 + s1) + (s2 + s3)) * 0.125f;
        s[j] = (j <= dr) ? sv : -1e30f;
        m = fmaxf(m, s[j]);
    }
    float lsum = 0.f;
#pragma unroll
    for (int j = 0; j < 16; ++j) {
        float w = (j <= dr) ? exp2f((s[j] - m) * L2E) : 0.f;
        s[j] = w;
        lsum += w;
    }
    float inv = 1.0f / lsum;
    float o[64];
#pragma unroll
    for (int d = 0; d < 64; ++d) o[d] = 0.f;
#pragma unroll
    for (int j = 0; j < 16; ++j) {
        float w = s[j];
#pragma unroll
        for (int d = 0; d < 64; ++d) o[d] = fmaf(w, vs[j][ho + ((d + rot) & 63)], o[d]);
    }
    size_t eo = ((tok0 + (size_t)dr * 128) << 9) + ho;
#pragma unroll
    for (int i = 0; i < 8; ++i) {
        _Float16 h8[8], l8[8];
#pragma unroll
        for (int j = 0; j < 8; ++j) {
            float y = o[i * 8 + j] * inv;
            _Float16 hh = (_Float16)y;
            h8[j] = hh;
            l8[j] = (_Float16)((y - (float)hh) * LOSCALE);
        }
        *(int4*)(xh + eo + (i << 3)) = *(int4*)h8;
        *(int4*)(xl + eo + (i << 3)) = *(int4*)l8;
    }
}

// ---- fused: out_xp = x; split(zL - x - bias_pre) -> xh/xl ----
__global__ __launch_bounds__(256) void xprior_xsrc_k(const float* __restrict__ zL,
                                                     const float* __restrict__ bias_pre,
                                                     const float* __restrict__ X,
                                                     float* __restrict__ out_xp,
                                                     _Float16* __restrict__ xh,
                                                     _Float16* __restrict__ xl) {
    int idx = blockIdx.x * 256 + threadIdx.x;
    int h = (idx & 63) << 3;
    size_t off = ((size_t)idx) << 3;
    float z[8], p[8], x[8];
    ld8f(zL + off, z);
    ld8f(bias_pre + h, p);
    ld8f(X + off, x);
    st8f(out_xp + off, x);
    _Float16 h8[8], l8[8];
#pragma unroll
    for (int i = 0; i < 8; ++i) {
        float y = z[i] - x[i] - p[i];
        _Float16 hh = (_Float16)y;
        h8[i] = hh;
        l8[i] = (_Float16)((y - (float)hh) * LOSCALE);
    }
    *(int4*)(xh + off) = *(int4*)h8;
    *(int4*)(xl + off) = *(int4*)l8;
}

// ---- 2-way fp16 scaled split: x = h + l*2^-12 ----
__global__ __launch_bounds__(256) void split2_k(const float* __restrict__ in,
                                                _Float16* __restrict__ ph,
                                                _Float16* __restrict__ pl) {
    int idx = blockIdx.x * 256 + threadIdx.x;
    float v[8];
    ld8f(in + (((size_t)idx) << 3), v);
    _Float16 h8[8], l8[8];
#pragma unroll
    for (int i = 0; i < 8; ++i) {
        _Float16 h = (_Float16)v[i];
        float r = v[i] - (float)h;          // exact
        h8[i] = h;
        l8[i] = (_Float16)(r * LOSCALE);
    }
    *(int4*)(ph + (((size_t)idx) << 3)) = *(int4*)h8;
    *(int4*)(pl + (((size_t)idx) << 3)) = *(int4*)l8;
}

// ---- 3-pass split-fp16 MFMA NT GEMM, 32x32x16, 128x64 tile, 2-phase dbuf ---
// SWZ=1: 1D grid, XCD-clustered -> each XCD owns 8 B col-panels (L2-resident).
// Requires gridDim.x = 64 * nrow (ncol fixed at 64).
#define LDT 34
template<int SWZ, bool ADD_C, bool BIAS>
__global__ __launch_bounds__(256) void gemm_f16_k(
        const _Float16* __restrict__ Xh, const _Float16* __restrict__ Xl,
        const _Float16* __restrict__ Wh, const _Float16* __restrict__ Wl,
        const float* __restrict__ bias, float* __restrict__ Cout, int ldc) {
    __shared__ _Float16 Ah[2][128][LDT], Al[2][128][LDT];
    __shared__ _Float16 Bh[2][64][LDT],  Bl[2][64][LDT];
    const int tid = threadIdx.x;
    int bm, bn;
    if (SWZ) {
        int id = blockIdx.x;
        int xcd = id & 7, ww = id >> 3;
        bn = ((xcd << 3) | (ww & 7)) << 6;   // col-panel: 8 per XCD
        bm = (ww >> 3) << 7;
    } else {
        bm = blockIdx.y << 7;
        bn = blockIdx.x << 6;
    }
    const int w = tid >> 6, lane = tid & 63;
    const int wr = w >> 1, wc = w & 1;
    const int l31 = lane & 31, hh = lane >> 5;
    const int ar0 = tid >> 2, akg = (tid & 3) << 3;
    const int ar1 = ar0 + 64;
    const _Float16* pXh0 = Xh + (size_t)(bm + ar0) * HDIM + akg;
    const _Float16* pXl0 = Xl + (size_t)(bm + ar0) * HDIM + akg;
    const _Float16* pXh1 = Xh + (size_t)(bm + ar1) * HDIM + akg;
    const _Float16* pXl1 = Xl + (size_t)(bm + ar1) * HDIM + akg;
    const _Float16* pWh  = Wh + (size_t)(bn + ar0) * HDIM + akg;
    const _Float16* pWl  = Wl + (size_t)(bn + ar0) * HDIM + akg;

    f32x16 acc1[2], acc2[2];
#pragma unroll
    for (int i = 0; i < 2; ++i)
#pragma unroll
        for (int r = 0; r < 16; ++r) { acc1[i][r] = 0.f; acc2[i][r] = 0.f; }

    int4 ra0h, ra0l, ra1h, ra1l, rbh, rbl;
    auto LOADR = [&](int k0) {
        ra0h = *(const int4*)(pXh0 + k0);
        ra0l = *(const int4*)(pXl0 + k0);
        ra1h = *(const int4*)(pXh1 + k0);
        ra1l = *(const int4*)(pXl1 + k0);
        rbh  = *(const int4*)(pWh + k0);
        rbl  = *(const int4*)(pWl + k0);
    };
    auto STORE = [&](int buf) {
        *(int4*)&Ah[buf][ar0][akg] = ra0h;
        *(int4*)&Al[buf][ar0][akg] = ra0l;
        *(int4*)&Ah[buf][ar1][akg] = ra1h;
        *(int4*)&Al[buf][ar1][akg] = ra1l;
        *(int4*)&Bh[buf][ar0][akg] = rbh;
        *(int4*)&Bl[buf][ar0][akg] = rbl;
    };

    LOADR(0);
    STORE(0);
    int cur = 0;
    for (int it = 0; it < 16; ++it) {
        if (it < 15) LOADR((it + 1) << 5);
        __syncthreads();
#pragma unroll
        for (int kh = 0; kh < 2; ++kh) {
            const int ko = (kh << 4) + (hh << 3);
            f16x8 fah[2], fal[2];
#pragma unroll
            for (int mf = 0; mf < 2; ++mf) {
                int ar = (wr << 6) + (mf << 5) + l31;
                fah[mf] = *(const f16x8*)&Ah[cur][ar][ko];
                fal[mf] = *(const f16x8*)&Al[cur][ar][ko];
            }
            int bc_ = (wc << 5) + l31;
            f16x8 bh = *(const f16x8*)&Bh[cur][bc_][ko];
            f16x8 bl = *(const f16x8*)&Bl[cur][bc_][ko];
#pragma unroll
            for (int mf = 0; mf < 2; ++mf) {
                acc1[mf] = __builtin_amdgcn_mfma_f32_32x32x16_f16(fah[mf], bh, acc1[mf], 0, 0, 0);
                acc2[mf] = __builtin_amdgcn_mfma_f32_32x32x16_f16(fah[mf], bl, acc2[mf], 0, 0, 0);
                acc2[mf] = __builtin_amdgcn_mfma_f32_32x32x16_f16(fal[mf], bh, acc2[mf], 0, 0, 0);
            }
        }
        if (it < 15) { STORE(cur ^ 1); cur ^= 1; }
    }
    const int col = bn + (wc << 5) + l31;
    const float badd = BIAS ? bias[col] : 0.f;
#pragma unroll
    for (int mf = 0; mf < 2; ++mf) {
#pragma unroll
        for (int r = 0; r < 16; ++r) {
            int row = bm + (wr << 6) + (mf << 5) + (r & 3) + ((r >> 2) << 3) + (hh << 2);
            float* cp = Cout + (size_t)row * ldc + col;
            float val = acc1[mf][r] + acc2[mf][r] * LOINV + badd;
            if (ADD_C) val += *cp;
            *cp = val;
        }
    }
}

// ---- per-row top-64: relu + exact radix select (early-exit) + scatter ----
__global__ __launch_bounds__(256) void topk_k(const float* __restrict__ logits,
                                              float* __restrict__ out) {
    const int row = blockIdx.x;
    const float* lr = logits + (((size_t)row) << 12);
    const int t = threadIdx.x;
    float v[16]; uint32_t u[16];
#pragma unroll
    for (int i = 0; i < 16; ++i) {
        float x = fmaxf(lr[t + (i << 8)], 0.f);
        v[i] = x;
        u[i] = __float_as_uint(x);
    }
    __shared__ int red[4];
    __shared__ unsigned long long bits[64];
    __shared__ int s_cut;
    uint32_t prefix = 0;
    bool exact = false;
    for (int bit = 30; bit >= 0; --bit) {
        uint32_t c = prefix | (1u << bit);
        int cnt = 0;
#pragma unroll
        for (int i = 0; i < 16; ++i) cnt += (u[i] >= c) ? 1 : 0;
#pragma unroll
        for (int off = 32; off; off >>= 1) cnt += __shfl_xor(cnt, off);
        if ((t & 63) == 0) red[t >> 6] = cnt;
        __syncthreads();
        int total = red[0] + red[1] + red[2] + red[3];
        __syncthreads();
        if (total >= 64) prefix = c;
        if (total == 64) { exact = true; break; }
    }
    float* orow = out + (((size_t)row) << 12);
    if (exact) {
#pragma unroll
        for (int i = 0; i < 16; ++i) {
            int col = t + (i << 8);
            orow[col] = (u[i] >= prefix) ? v[i] : 0.f;
        }
        return;
    }
    const uint32_t T64 = prefix;
    int cg = 0;
#pragma unroll
    for (int i = 0; i < 16; ++i) cg += (u[i] > T64) ? 1 : 0;
#pragma unroll
    for (int off = 32; off; off >>= 1) cg += __shfl_xor(cg, off);
    if ((t & 63) == 0) red[t >> 6] = cg;
    __syncthreads();
    const int ngt = red[0] + red[1] + red[2] + red[3];
    int cut = -1;
    if (T64 != 0u) {
        const int r = 64 - ngt;
        if (t < 64) bits[t] = 0ull;
        __syncthreads();
#pragma unroll
        for (int i = 0; i < 16; ++i) {
            if (u[i] == T64) {
                int col = t + (i << 8);
                atomicOr(&bits[col >> 6], 1ull << (col & 63));
            }
        }
        __syncthreads();
        if (t == 0) {
            int need = r, cs = FDIM - 1;
            for (int wd = 0; wd < 64; ++wd) {
                int pc = __popcll(bits[wd]);
                if (need <= pc) {
                    unsigned long long bb = bits[wd];
                    for (int q = 1; q < need; ++q) bb &= bb - 1;
                    cs = (wd << 6) + (__ffsll(bb) - 1);
                    break;
                }
                need -= pc;
            }
            s_cut = cs;
        }
        __syncthreads();
        cut = s_cut;
    }
#pragma unroll
    for (int i = 0; i < 16; ++i) {
        int col = t + (i << 8);
        bool keep = (u[i] > T64) || (T64 != 0u && u[i] == T64 && col <= cut);
        orow[col] = keep ? v[i] : 0.f;
    }
}

extern "C" void kernel_launch(void* const* d_in, const int* in_sizes, int n_in,
                              void* d_out, int out_size, void* d_ws, size_t ws_size,
                              hipStream_t stream) {
    const float* zL      = (const float*)d_in[0];
    const float* gamma_l = (const float*)d_in[5];
    const float* beta_l  = (const float*)d_in[6];
    const float* gamma_d = (const float*)d_in[11];
    const float* beta_d  = (const float*)d_in[12];
    const float* dict_e  = (const float*)d_in[13];
    const float* bias_pre= (const float*)d_in[14];
    const float* bias_enc= (const float*)d_in[15];
    const float* qt      = (const float*)d_in[16];
    const float* wproj[8] = { (const float*)d_in[1], (const float*)d_in[2],
                              (const float*)d_in[3], (const float*)d_in[4],
                              (const float*)d_in[7], (const float*)d_in[8],
                              (const float*)d_in[9], (const float*)d_in[10] };

    float* out_z  = (float*)d_out;
    float* out_xp = out_z + (size_t)NTOK * FDIM;

    const size_t NHf = (size_t)NTOK * HDIM;
    float* B0 = (float*)d_out;         // residual X (z_n region)
    float* B1 = B0 + NHf;              // fused QKV [16384][1536]

    float* wsf    = (float*)d_ws;
    float* logits = wsf + 64;

    const size_t dictE = (size_t)FDIM * HDIM;
    const size_t WE    = (size_t)HDIM * HDIM;

    int crows = 2048;                  // L3-resident logits chunk
    const size_t fixedB = 64 * sizeof(float)
                        + (2 * dictE + 16 * WE + 2 * NHf) * sizeof(_Float16);
    while (crows > 128 && fixedB + (size_t)crows * FDIM * sizeof(float) > ws_size)
        crows >>= 1;

    _Float16* dh  = (_Float16*)(logits + (size_t)crows * FDIM);
    _Float16* dl  = dh + dictE;
    _Float16* wsp = dh + 2 * dictE;
    _Float16* xh  = wsp + 16 * WE;
    _Float16* xl  = xh + NHf;
    _Float16* qkvh_l = wsp;
    _Float16* qkvl_l = wsp + 3 * WE;
    _Float16* woh_l  = wsp + 6 * WE;
    _Float16* wol_l  = wsp + 7 * WE;
    _Float16* qkvh_d = wsp + 8 * WE;
    _Float16* qkvl_d = wsp + 11 * WE;
    _Float16* woh_d  = wsp + 14 * WE;
    _Float16* wol_d  = wsp + 15 * WE;

    const dim3 blk256(256), blk128(128), blk512(512);
    const dim3 gElem(4096);
    const dim3 gW(WE / 8 / 256);
    const dim3 gQKV(QKVD / 64, NTOK / 128);
    const dim3 gWo(HDIM / 64, NTOK / 128);

    split2_k<<<gW, blk256, 0, stream>>>(wproj[0], qkvh_l,          qkvl_l);
    split2_k<<<gW, blk256, 0, stream>>>(wproj[1], qkvh_l + WE,     qkvl_l + WE);
    split2_k<<<gW, blk256, 0, stream>>>(wproj[2], qkvh_l + 2 * WE, qkvl_l + 2 * WE);
    split2_k<<<gW, blk256, 0, stream>>>(wproj[3], woh_l,           wol_l);
    split2_k<<<gW, blk256, 0, stream>>>(wproj[4], qkvh_d,          qkvl_d);
    split2_k<<<gW, blk256, 0, stream>>>(wproj[5], qkvh_d + WE,     qkvl_d + WE);
    split2_k<<<gW, blk256, 0, stream>>>(wproj[6], qkvh_d + 2 * WE, qkvl_d + 2 * WE);
    split2_k<<<gW, blk256, 0, stream>>>(wproj[7], woh_d,           wol_d);
    split2_k<<<dim3(dictE / 8 / 256), blk256, 0, stream>>>(dict_e, dh, dl);

    build_x_k<<<gElem, blk256, 0, stream>>>(zL, qt, B0);

    // ---- layer attention block ----
    ln_split_k<<<dim3(NTOK / 4), blk256, 0, stream>>>(B0, gamma_l, beta_l, xh, xl);
    gemm_f16_k<0, false, false><<<gQKV, blk256, 0, stream>>>(xh, xl, qkvh_l, qkvl_l, nullptr, B1, QKVD);
    attn_l_k<<<dim3(128, NHEAD), blk512, 0, stream>>>(B1, xh, xl);
    gemm_f16_k<0, true, false><<<gWo, blk256, 0, stream>>>(xh, xl, woh_l, wol_l, nullptr, B0, HDIM);

    // ---- depth attention block ----
    ln_split_k<<<dim3(NTOK / 4), blk256, 0, stream>>>(B0, gamma_d, beta_d, xh, xl);
    gemm_f16_k<0, false, false><<<gQKV, blk256, 0, stream>>>(xh, xl, qkvh_d, qkvl_d, nullptr, B1, QKVD);
    attn_d_k<<<dim3(1024), blk128, 0, stream>>>(B1, xh, xl);
    gemm_f16_k<0, true, false><<<gWo, blk256, 0, stream>>>(xh, xl, woh_d, wol_d, nullptr, B0, HDIM);

    // ---- x_prior out + x_src split ----
    xprior_xsrc_k<<<gElem, blk256, 0, stream>>>(zL, bias_pre, B0, out_xp, xh, xl);

    for (int c0 = 0; c0 < NTOK; c0 += crows) {
        if ((crows & 127) == 0 && (crows / 128) * 64 % 8 == 0) {
            // XCD-clustered 1D grid: 64 col-panels x (crows/128) row-panels
            gemm_f16_k<1, false, true><<<dim3(64 * (crows / 128)), blk256, 0, stream>>>(
                xh + (size_t)c0 * HDIM, xl + (size_t)c0 * HDIM,
                dh, dl, bias_enc, logits, FDIM);
        } else {
            gemm_f16_k<0, false, true><<<dim3(FDIM / 64, crows / 128), blk256, 0, stream>>>(
                xh + (size_t)c0 * HDIM, xl + (size_t)c0 * HDIM,
                dh, dl, bias_enc, logits, FDIM);
        }
        topk_k<<<dim3(crows), blk256, 0, stream>>>(logits, out_z + (size_t)c0 * FDIM);
    }
}

// Round 18
// 1067.143 us; speedup vs baseline: 1.1173x; 1.0928x over previous
//
#include <hip/hip_runtime.h>
#include <stdint.h>

#define NTOK 16384        // B*D*L = 8*16*128
#define HDIM 512
#define FDIM 4096
#define NHEAD 8
#define QKVD 1536         // fused QKV row width
#define L2E 1.44269504f   // log2(e)

typedef __attribute__((ext_vector_type(8))) _Float16 f16x8;
typedef __attribute__((ext_vector_type(16))) float f32x16;
#define LOSCALE 4096.0f
#define LOINV   (1.0f / 4096.0f)

static __device__ __forceinline__ void ld8f(const float* p, float* v) {
    *(float4*)&v[0] = *(const float4*)p;
    *(float4*)&v[4] = *(const float4*)(p + 4);
}
static __device__ __forceinline__ void st8f(float* p, const float* v) {
    *(float4*)p       = *(const float4*)&v[0];
    *(float4*)(p + 4) = *(const float4*)&v[4];
}
static __device__ __forceinline__ uint32_t packsplit(float v) {
    _Float16 h = (_Float16)v;
    _Float16 l = (_Float16)((v - (float)h) * LOSCALE);
    union { _Float16 f; uint16_t u; } ch{h}, cl{l};
    return (uint32_t)ch.u | ((uint32_t)cl.u << 16);
}
static __device__ __forceinline__ void unpack8(const uint32_t* p, f16x8* h, f16x8* l) {
    union { uint16_t s[8]; f16x8 v; } uh, ul;
#pragma unroll
    for (int i = 0; i < 8; ++i) {
        uint32_t x = p[i];
        uh.s[i] = (uint16_t)(x & 0xffffu);
        ul.s[i] = (uint16_t)(x >> 16);
    }
    *h = uh.v;
    *l = ul.v;
}

// ---- x0 = concat(query_token, zL[:, :-1]) -> f32 ----
__global__ __launch_bounds__(256) void build_x_k(const float* __restrict__ zL,
                                                 const float* __restrict__ qt,
                                                 float* __restrict__ X) {
    int idx = blockIdx.x * 256 + threadIdx.x;
    int n = idx >> 6;
    int h = (idx & 63) << 3;
    int d = (n >> 7) & 15;
    const float* src = d ? (zL + (((size_t)(n - 128)) << 9) + h) : (qt + h);
    float v[8];
    ld8f(src, v);
    st8f(X + (((size_t)n) << 9) + h, v);
}

// ---- fused LN stats + LN + fp16 2-way split (one wave per row) ----
__global__ __launch_bounds__(256) void ln_split_k(const float* __restrict__ X,
                                                  const float* __restrict__ gamma,
                                                  const float* __restrict__ beta,
                                                  _Float16* __restrict__ ph,
                                                  _Float16* __restrict__ pl) {
    int row = blockIdx.x * 4 + (threadIdx.x >> 6);
    int lane = threadIdx.x & 63;
    int h = lane << 3;
    const float* xr = X + (((size_t)row) << 9) + h;
    float v[8];
    ld8f(xr, v);
    float s = 0.f;
#pragma unroll
    for (int i = 0; i < 8; ++i) s += v[i];
#pragma unroll
    for (int off = 32; off; off >>= 1) s += __shfl_xor(s, off);
    float m = s * (1.0f / 512.0f);
    float q = 0.f;
#pragma unroll
    for (int i = 0; i < 8; ++i) { float d = v[i] - m; q += d * d; }
#pragma unroll
    for (int off = 32; off; off >>= 1) q += __shfl_xor(q, off);
    float rs = 1.0f / sqrtf(q * (1.0f / 512.0f) + 1e-5f);
    float gv[8], be[8];
    ld8f(gamma + h, gv);
    ld8f(beta + h, be);
    _Float16 h8[8], l8[8];
#pragma unroll
    for (int i = 0; i < 8; ++i) {
        float y = (v[i] - m) * rs * gv[i] + be[i];
        _Float16 hh = (_Float16)y;
        h8[i] = hh;
        l8[i] = (_Float16)((y - (float)hh) * LOSCALE);
    }
    size_t off = (((size_t)row) << 9) + h;
    *(int4*)(ph + off) = *(int4*)h8;
    *(int4*)(pl + off) = *(int4*)l8;
}

// ---- non-causal attention over L via split-fp16 MFMA flash block -----------
// One (seq, head) per block, 256 threads / 4 waves.
// LDS pool (u32): Qp[128][65] @0, Kp[128][65] @8320, Vt[64][129] @16640,
// rl[128] @24896; S/P[128][129] aliases Qp/Kp after QK^T (16512 <= 16640).
__global__ __launch_bounds__(256) void attn_l_k(const float* __restrict__ QKV,
                                                _Float16* __restrict__ xh,
                                                _Float16* __restrict__ xl) {
    __shared__ uint32_t pool[25024];
    uint32_t* Qp = pool;
    uint32_t* Kp = pool + 8320;
    uint32_t* Vt = pool + 16640;
    float*    rl = (float*)(pool + 24896);
    uint32_t* S  = pool;                 // phase 2+ (aliases Qp/Kp)

    const int seq = blockIdx.x, head = blockIdx.y;
    const int t = threadIdx.x;
    const size_t tok0 = (size_t)seq << 7;
    const int ho = head << 6;
    const int w = t >> 6, lane = t & 63;
    const int wr = w >> 1, wc = w & 1;
    const int l31 = lane & 31, hh = lane >> 5;

    // ---- phase 0: stage Q,K packed-split; V transposed packed-split ----
#pragma unroll
    for (int i = 0; i < 8; ++i) {
        int idx = t + (i << 8);
        int row = idx >> 4, c4 = (idx & 15) << 2;
        size_t g = (tok0 + row) * QKVD + ho + c4;
        float4 qv = *(const float4*)(QKV + g);
        float4 kv = *(const float4*)(QKV + g + 512);
        float4 vv = *(const float4*)(QKV + g + 1024);
        uint32_t* qd = Qp + row * 65 + c4;
        qd[0] = packsplit(qv.x); qd[1] = packsplit(qv.y);
        qd[2] = packsplit(qv.z); qd[3] = packsplit(qv.w);
        uint32_t* kd = Kp + row * 65 + c4;
        kd[0] = packsplit(kv.x); kd[1] = packsplit(kv.y);
        kd[2] = packsplit(kv.z); kd[3] = packsplit(kv.w);
        Vt[(c4 + 0) * 129 + row] = packsplit(vv.x);
        Vt[(c4 + 1) * 129 + row] = packsplit(vv.y);
        Vt[(c4 + 2) * 129 + row] = packsplit(vv.z);
        Vt[(c4 + 3) * 129 + row] = packsplit(vv.w);
    }
    __syncthreads();

    // ---- phase 1: S = 0.125 * Q K^T (3-pass split), wave tile 64x64 ----
    f32x16 a1[2][2], a2[2][2];
#pragma unroll
    for (int i = 0; i < 2; ++i)
#pragma unroll
        for (int j = 0; j < 2; ++j)
#pragma unroll
            for (int r = 0; r < 16; ++r) { a1[i][j][r] = 0.f; a2[i][j][r] = 0.f; }
#pragma unroll
    for (int ks = 0; ks < 4; ++ks) {
        const int ko = (ks << 4) + (hh << 3);
        f16x8 qh[2], ql[2], kh[2], kl[2];
#pragma unroll
        for (int mf = 0; mf < 2; ++mf)
            unpack8(Qp + ((wr << 6) + (mf << 5) + l31) * 65 + ko, &qh[mf], &ql[mf]);
#pragma unroll
        for (int nf = 0; nf < 2; ++nf)
            unpack8(Kp + ((wc << 6) + (nf << 5) + l31) * 65 + ko, &kh[nf], &kl[nf]);
#pragma unroll
        for (int nf = 0; nf < 2; ++nf)
#pragma unroll
            for (int mf = 0; mf < 2; ++mf) {
                a1[mf][nf] = __builtin_amdgcn_mfma_f32_32x32x16_f16(qh[mf], kh[nf], a1[mf][nf], 0, 0, 0);
                a2[mf][nf] = __builtin_amdgcn_mfma_f32_32x32x16_f16(qh[mf], kl[nf], a2[mf][nf], 0, 0, 0);
                a2[mf][nf] = __builtin_amdgcn_mfma_f32_32x32x16_f16(ql[mf], kh[nf], a2[mf][nf], 0, 0, 0);
            }
    }
    __syncthreads();                     // all Q/K reads complete
#pragma unroll
    for (int mf = 0; mf < 2; ++mf)
#pragma unroll
        for (int nf = 0; nf < 2; ++nf) {
            int col = (wc << 6) + (nf << 5) + l31;
#pragma unroll
            for (int r = 0; r < 16; ++r) {
                int row = (wr << 6) + (mf << 5) + (r & 3) + ((r >> 2) << 3) + (hh << 2);
                float sv = (a1[mf][nf][r] + a2[mf][nf][r] * LOINV) * 0.125f;
                S[row * 129 + col] = __float_as_uint(sv);
            }
        }
    __syncthreads();

    // ---- phase 2: row softmax; P packed-split in place; rl = 1/sum ----
    {
        int row = t >> 1, half = t & 1;
        uint32_t* sr = S + row * 129 + (half << 6);
        float mx = -1e30f;
#pragma unroll
        for (int j = 0; j < 64; ++j) mx = fmaxf(mx, __uint_as_float(sr[j]));
        mx = fmaxf(mx, __shfl_xor(mx, 1));
        float sum = 0.f;
#pragma unroll
        for (int j = 0; j < 64; ++j) {
            float wg = exp2f((__uint_as_float(sr[j]) - mx) * L2E);
            sum += wg;
            sr[j] = packsplit(wg);
        }
        sum += __shfl_xor(sum, 1);
        if (!half) rl[row] = 1.0f / sum;
    }
    __syncthreads();

    // ---- phase 3: O = P V (3-pass split), wave tile 64 rows x 32 cols ----
    f32x16 o1[2], o2[2];
#pragma unroll
    for (int i = 0; i < 2; ++i)
#pragma unroll
        for (int r = 0; r < 16; ++r) { o1[i][r] = 0.f; o2[i][r] = 0.f; }
    const int dcol = (wc << 5) + l31;
#pragma unroll
    for (int ks = 0; ks < 8; ++ks) {
        const int jo = (ks << 4) + (hh << 3);
        f16x8 ph[2], pl2[2], vh, vl;
#pragma unroll
        for (int mf = 0; mf < 2; ++mf)
            unpack8(S + ((wr << 6) + (mf << 5) + l31) * 129 + jo, &ph[mf], &pl2[mf]);
        unpack8(Vt + dcol * 129 + jo, &vh, &vl);
#pragma unroll
        for (int mf = 0; mf < 2; ++mf) {
            o1[mf] = __builtin_amdgcn_mfma_f32_32x32x16_f16(ph[mf], vh, o1[mf], 0, 0, 0);
            o2[mf] = __builtin_amdgcn_mfma_f32_32x32x16_f16(ph[mf], vl, o2[mf], 0, 0, 0);
            o2[mf] = __builtin_amdgcn_mfma_f32_32x32x16_f16(pl2[mf], vh, o2[mf], 0, 0, 0);
        }
    }
#pragma unroll
    for (int mf = 0; mf < 2; ++mf)
#pragma unroll
        for (int r = 0; r < 16; ++r) {
            int row = (wr << 6) + (mf << 5) + (r & 3) + ((r >> 2) << 3) + (hh << 2);
            float y = (o1[mf][r] + o2[mf][r] * LOINV) * rl[row];
            size_t eo = ((tok0 + row) << 9) + ho + dcol;
            _Float16 hv = (_Float16)y;
            xh[eo] = hv;
            xl[eo] = (_Float16)((y - (float)hv) * LOSCALE);
        }
}

// ---- causal attention over D; per-head col rotation (bank-conflict-free) ---
__global__ __launch_bounds__(128) void attn_d_k(const float* __restrict__ QKV,
                                                _Float16* __restrict__ xh,
                                                _Float16* __restrict__ xl) {
    __shared__ float ks[16][512];
    __shared__ float vs[16][512];
    const int bl = blockIdx.x;
    const int b = bl >> 7, l = bl & 127;
    const int t = threadIdx.x;
    const size_t tok0 = (size_t)b * 2048 + l;
#pragma unroll
    for (int i = 0; i < 16; ++i) {
        int c4 = t << 2;
        int hc = c4 >> 6;
        int p  = (c4 & ~63) | ((c4 + (hc << 2)) & 63);
        size_t g = (tok0 + (size_t)i * 128) * QKVD + c4;
        *(float4*)&ks[i][p] = *(const float4*)(QKV + g + 512);
        *(float4*)&vs[i][p] = *(const float4*)(QKV + g + 1024);
    }
    __syncthreads();
    const int head = t >> 4, dr = t & 15;
    const int ho = head << 6;
    const int rot = head << 2;
    float qr[64];
    const float* qp = QKV + (tok0 + (size_t)dr * 128) * QKVD + ho;
#pragma unroll
    for (int i = 0; i < 16; ++i) *(float4*)&qr[i << 2] = *(const float4*)(qp + (i << 2));
    float s[16];
    float m = -1e30f;
#pragma unroll
    for (int j = 0; j < 16; ++j) {
        float s0 = 0.f, s1 = 0.f, s2 = 0.f, s3 = 0.f;
#pragma unroll
        for (int d = 0; d < 64; d += 4) {
            s0 = fmaf(qr[d + 0], ks[j][ho + ((d + 0 + rot) & 63)], s0);
            s1 = fmaf(qr[d + 1], ks[j][ho + ((d + 1 + rot) & 63)], s1);
            s2 = fmaf(qr[d + 2], ks[j][ho + ((d + 2 + rot) & 63)], s2);
            s3 = fmaf(qr[d + 3], ks[j][ho + ((d + 3 + rot) & 63)], s3);
        }
        float sv = ((s0 + s1) + (s2 + s3)) * 0.125f;
        s[j] = (j <= dr) ? sv : -1e30f;
        m = fmaxf(m, s[j]);
    }
    float lsum = 0.f;
#pragma unroll
    for (int j = 0; j < 16; ++j) {
        float w = (j <= dr) ? exp2f((s[j] - m) * L2E) : 0.f;
        s[j] = w;
        lsum += w;
    }
    float inv = 1.0f / lsum;
    float o[64];
#pragma unroll
    for (int d = 0; d < 64; ++d) o[d] = 0.f;
#pragma unroll
    for (int j = 0; j < 16; ++j) {
        float w = s[j];
#pragma unroll
        for (int d = 0; d < 64; ++d) o[d] = fmaf(w, vs[j][ho + ((d + rot) & 63)], o[d]);
    }
    size_t eo = ((tok0 + (size_t)dr * 128) << 9) + ho;
#pragma unroll
    for (int i = 0; i < 8; ++i) {
        _Float16 h8[8], l8[8];
#pragma unroll
        for (int j = 0; j < 8; ++j) {
            float y = o[i * 8 + j] * inv;
            _Float16 hh = (_Float16)y;
            h8[j] = hh;
            l8[j] = (_Float16)((y - (float)hh) * LOSCALE);
        }
        *(int4*)(xh + eo + (i << 3)) = *(int4*)h8;
        *(int4*)(xl + eo + (i << 3)) = *(int4*)l8;
    }
}

// ---- fused: out_xp = x; split(zL - x - bias_pre) -> xh/xl ----
__global__ __launch_bounds__(256) void xprior_xsrc_k(const float* __restrict__ zL,
                                                     const float* __restrict__ bias_pre,
                                                     const float* __restrict__ X,
                                                     float* __restrict__ out_xp,
                                                     _Float16* __restrict__ xh,
                                                     _Float16* __restrict__ xl) {
    int idx = blockIdx.x * 256 + threadIdx.x;
    int h = (idx & 63) << 3;
    size_t off = ((size_t)idx) << 3;
    float z[8], p[8], x[8];
    ld8f(zL + off, z);
    ld8f(bias_pre + h, p);
    ld8f(X + off, x);
    st8f(out_xp + off, x);
    _Float16 h8[8], l8[8];
#pragma unroll
    for (int i = 0; i < 8; ++i) {
        float y = z[i] - x[i] - p[i];
        _Float16 hh = (_Float16)y;
        h8[i] = hh;
        l8[i] = (_Float16)((y - (float)hh) * LOSCALE);
    }
    *(int4*)(xh + off) = *(int4*)h8;
    *(int4*)(xl + off) = *(int4*)l8;
}

// ---- 2-way fp16 scaled split: x = h + l*2^-12 ----
__global__ __launch_bounds__(256) void split2_k(const float* __restrict__ in,
                                                _Float16* __restrict__ ph,
                                                _Float16* __restrict__ pl) {
    int idx = blockIdx.x * 256 + threadIdx.x;
    float v[8];
    ld8f(in + (((size_t)idx) << 3), v);
    _Float16 h8[8], l8[8];
#pragma unroll
    for (int i = 0; i < 8; ++i) {
        _Float16 h = (_Float16)v[i];
        float r = v[i] - (float)h;          // exact
        h8[i] = h;
        l8[i] = (_Float16)(r * LOSCALE);
    }
    *(int4*)(ph + (((size_t)idx) << 3)) = *(int4*)h8;
    *(int4*)(pl + (((size_t)idx) << 3)) = *(int4*)l8;
}

// ---- 3-pass split-fp16 MFMA NT GEMM, 32x32x16, 128x64 tile, 2-phase dbuf ---
#define LDT 34
template<int SWZ, bool ADD_C, bool BIAS>
__global__ __launch_bounds__(256) void gemm_f16_k(
        const _Float16* __restrict__ Xh, const _Float16* __restrict__ Xl,
        const _Float16* __restrict__ Wh, const _Float16* __restrict__ Wl,
        const float* __restrict__ bias, float* __restrict__ Cout, int ldc) {
    __shared__ _Float16 Ah[2][128][LDT], Al[2][128][LDT];
    __shared__ _Float16 Bh[2][64][LDT],  Bl[2][64][LDT];
    const int tid = threadIdx.x;
    int bm, bn;
    if (SWZ) {
        int id = blockIdx.x;
        int xcd = id & 7, ww = id >> 3;
        bn = ((xcd << 3) | (ww & 7)) << 6;
        bm = (ww >> 3) << 7;
    } else {
        bm = blockIdx.y << 7;
        bn = blockIdx.x << 6;
    }
    const int w = tid >> 6, lane = tid & 63;
    const int wr = w >> 1, wc = w & 1;
    const int l31 = lane & 31, hh = lane >> 5;
    const int ar0 = tid >> 2, akg = (tid & 3) << 3;
    const int ar1 = ar0 + 64;
    const _Float16* pXh0 = Xh + (size_t)(bm + ar0) * HDIM + akg;
    const _Float16* pXl0 = Xl + (size_t)(bm + ar0) * HDIM + akg;
    const _Float16* pXh1 = Xh + (size_t)(bm + ar1) * HDIM + akg;
    const _Float16* pXl1 = Xl + (size_t)(bm + ar1) * HDIM + akg;
    const _Float16* pWh  = Wh + (size_t)(bn + ar0) * HDIM + akg;
    const _Float16* pWl  = Wl + (size_t)(bn + ar0) * HDIM + akg;

    f32x16 acc1[2], acc2[2];
#pragma unroll
    for (int i = 0; i < 2; ++i)
#pragma unroll
        for (int r = 0; r < 16; ++r) { acc1[i][r] = 0.f; acc2[i][r] = 0.f; }

    int4 ra0h, ra0l, ra1h, ra1l, rbh, rbl;
    auto LOADR = [&](int k0) {
        ra0h = *(const int4*)(pXh0 + k0);
        ra0l = *(const int4*)(pXl0 + k0);
        ra1h = *(const int4*)(pXh1 + k0);
        ra1l = *(const int4*)(pXl1 + k0);
        rbh  = *(const int4*)(pWh + k0);
        rbl  = *(const int4*)(pWl + k0);
    };
    auto STORE = [&](int buf) {
        *(int4*)&Ah[buf][ar0][akg] = ra0h;
        *(int4*)&Al[buf][ar0][akg] = ra0l;
        *(int4*)&Ah[buf][ar1][akg] = ra1h;
        *(int4*)&Al[buf][ar1][akg] = ra1l;
        *(int4*)&Bh[buf][ar0][akg] = rbh;
        *(int4*)&Bl[buf][ar0][akg] = rbl;
    };

    LOADR(0);
    STORE(0);
    int cur = 0;
    for (int it = 0; it < 16; ++it) {
        if (it < 15) LOADR((it + 1) << 5);
        __syncthreads();
#pragma unroll
        for (int kh = 0; kh < 2; ++kh) {
            const int ko = (kh << 4) + (hh << 3);
            f16x8 fah[2], fal[2];
#pragma unroll
            for (int mf = 0; mf < 2; ++mf) {
                int ar = (wr << 6) + (mf << 5) + l31;
                fah[mf] = *(const f16x8*)&Ah[cur][ar][ko];
                fal[mf] = *(const f16x8*)&Al[cur][ar][ko];
            }
            int bc_ = (wc << 5) + l31;
            f16x8 bh = *(const f16x8*)&Bh[cur][bc_][ko];
            f16x8 bl = *(const f16x8*)&Bl[cur][bc_][ko];
#pragma unroll
            for (int mf = 0; mf < 2; ++mf) {
                acc1[mf] = __builtin_amdgcn_mfma_f32_32x32x16_f16(fah[mf], bh, acc1[mf], 0, 0, 0);
                acc2[mf] = __builtin_amdgcn_mfma_f32_32x32x16_f16(fah[mf], bl, acc2[mf], 0, 0, 0);
                acc2[mf] = __builtin_amdgcn_mfma_f32_32x32x16_f16(fal[mf], bh, acc2[mf], 0, 0, 0);
            }
        }
        if (it < 15) { STORE(cur ^ 1); cur ^= 1; }
    }
    const int col = bn + (wc << 5) + l31;
    const float badd = BIAS ? bias[col] : 0.f;
#pragma unroll
    for (int mf = 0; mf < 2; ++mf) {
#pragma unroll
        for (int r = 0; r < 16; ++r) {
            int row = bm + (wr << 6) + (mf << 5) + (r & 3) + ((r >> 2) << 3) + (hh << 2);
            float* cp = Cout + (size_t)row * ldc + col;
            float val = acc1[mf][r] + acc2[mf][r] * LOINV + badd;
            if (ADD_C) val += *cp;
            *cp = val;
        }
    }
}

// ---- per-row top-64: relu + exact radix select (early-exit) + scatter ----
__global__ __launch_bounds__(256) void topk_k(const float* __restrict__ logits,
                                              float* __restrict__ out) {
    const int row = blockIdx.x;
    const float* lr = logits + (((size_t)row) << 12);
    const int t = threadIdx.x;
    float v[16]; uint32_t u[16];
#pragma unroll
    for (int i = 0; i < 16; ++i) {
        float x = fmaxf(lr[t + (i << 8)], 0.f);
        v[i] = x;
        u[i] = __float_as_uint(x);
    }
    __shared__ int red[4];
    __shared__ unsigned long long bits[64];
    __shared__ int s_cut;
    uint32_t prefix = 0;
    bool exact = false;
    for (int bit = 30; bit >= 0; --bit) {
        uint32_t c = prefix | (1u << bit);
        int cnt = 0;
#pragma unroll
        for (int i = 0; i < 16; ++i) cnt += (u[i] >= c) ? 1 : 0;
#pragma unroll
        for (int off = 32; off; off >>= 1) cnt += __shfl_xor(cnt, off);
        if ((t & 63) == 0) red[t >> 6] = cnt;
        __syncthreads();
        int total = red[0] + red[1] + red[2] + red[3];
        __syncthreads();
        if (total >= 64) prefix = c;
        if (total == 64) { exact = true; break; }
    }
    float* orow = out + (((size_t)row) << 12);
    if (exact) {
#pragma unroll
        for (int i = 0; i < 16; ++i) {
            int col = t + (i << 8);
            orow[col] = (u[i] >= prefix) ? v[i] : 0.f;
        }
        return;
    }
    const uint32_t T64 = prefix;
    int cg = 0;
#pragma unroll
    for (int i = 0; i < 16; ++i) cg += (u[i] > T64) ? 1 : 0;
#pragma unroll
    for (int off = 32; off; off >>= 1) cg += __shfl_xor(cg, off);
    if ((t & 63) == 0) red[t >> 6] = cg;
    __syncthreads();
    const int ngt = red[0] + red[1] + red[2] + red[3];
    int cut = -1;
    if (T64 != 0u) {
        const int r = 64 - ngt;
        if (t < 64) bits[t] = 0ull;
        __syncthreads();
#pragma unroll
        for (int i = 0; i < 16; ++i) {
            if (u[i] == T64) {
                int col = t + (i << 8);
                atomicOr(&bits[col >> 6], 1ull << (col & 63));
            }
        }
        __syncthreads();
        if (t == 0) {
            int need = r, cs = FDIM - 1;
            for (int wd = 0; wd < 64; ++wd) {
                int pc = __popcll(bits[wd]);
                if (need <= pc) {
                    unsigned long long bb = bits[wd];
                    for (int q = 1; q < need; ++q) bb &= bb - 1;
                    cs = (wd << 6) + (__ffsll(bb) - 1);
                    break;
                }
                need -= pc;
            }
            s_cut = cs;
        }
        __syncthreads();
        cut = s_cut;
    }
#pragma unroll
    for (int i = 0; i < 16; ++i) {
        int col = t + (i << 8);
        bool keep = (u[i] > T64) || (T64 != 0u && u[i] == T64 && col <= cut);
        orow[col] = keep ? v[i] : 0.f;
    }
}

extern "C" void kernel_launch(void* const* d_in, const int* in_sizes, int n_in,
                              void* d_out, int out_size, void* d_ws, size_t ws_size,
                              hipStream_t stream) {
    const float* zL      = (const float*)d_in[0];
    const float* gamma_l = (const float*)d_in[5];
    const float* beta_l  = (const float*)d_in[6];
    const float* gamma_d = (const float*)d_in[11];
    const float* beta_d  = (const float*)d_in[12];
    const float* dict_e  = (const float*)d_in[13];
    const float* bias_pre= (const float*)d_in[14];
    const float* bias_enc= (const float*)d_in[15];
    const float* qt      = (const float*)d_in[16];
    const float* wproj[8] = { (const float*)d_in[1], (const float*)d_in[2],
                              (const float*)d_in[3], (const float*)d_in[4],
                              (const float*)d_in[7], (const float*)d_in[8],
                              (const float*)d_in[9], (const float*)d_in[10] };

    float* out_z  = (float*)d_out;
    float* out_xp = out_z + (size_t)NTOK * FDIM;

    const size_t NHf = (size_t)NTOK * HDIM;
    float* B0 = (float*)d_out;         // residual X (z_n region)
    float* B1 = B0 + NHf;              // fused QKV [16384][1536]

    float* wsf    = (float*)d_ws;
    float* logits = wsf + 64;

    const size_t dictE = (size_t)FDIM * HDIM;
    const size_t WE    = (size_t)HDIM * HDIM;

    int crows = 2048;                  // L3-resident logits chunk
    const size_t fixedB = 64 * sizeof(float)
                        + (2 * dictE + 16 * WE + 2 * NHf) * sizeof(_Float16);
    while (crows > 128 && fixedB + (size_t)crows * FDIM * sizeof(float) > ws_size)
        crows >>= 1;

    _Float16* dh  = (_Float16*)(logits + (size_t)crows * FDIM);
    _Float16* dl  = dh + dictE;
    _Float16* wsp = dh + 2 * dictE;
    _Float16* xh  = wsp + 16 * WE;
    _Float16* xl  = xh + NHf;
    _Float16* qkvh_l = wsp;
    _Float16* qkvl_l = wsp + 3 * WE;
    _Float16* woh_l  = wsp + 6 * WE;
    _Float16* wol_l  = wsp + 7 * WE;
    _Float16* qkvh_d = wsp + 8 * WE;
    _Float16* qkvl_d = wsp + 11 * WE;
    _Float16* woh_d  = wsp + 14 * WE;
    _Float16* wol_d  = wsp + 15 * WE;

    const dim3 blk256(256), blk128(128);
    const dim3 gElem(4096);
    const dim3 gW(WE / 8 / 256);
    const dim3 gQKV(QKVD / 64, NTOK / 128);
    const dim3 gWo(HDIM / 64, NTOK / 128);

    split2_k<<<gW, blk256, 0, stream>>>(wproj[0], qkvh_l,          qkvl_l);
    split2_k<<<gW, blk256, 0, stream>>>(wproj[1], qkvh_l + WE,     qkvl_l + WE);
    split2_k<<<gW, blk256, 0, stream>>>(wproj[2], qkvh_l + 2 * WE, qkvl_l + 2 * WE);
    split2_k<<<gW, blk256, 0, stream>>>(wproj[3], woh_l,           wol_l);
    split2_k<<<gW, blk256, 0, stream>>>(wproj[4], qkvh_d,          qkvl_d);
    split2_k<<<gW, blk256, 0, stream>>>(wproj[5], qkvh_d + WE,     qkvl_d + WE);
    split2_k<<<gW, blk256, 0, stream>>>(wproj[6], qkvh_d + 2 * WE, qkvl_d + 2 * WE);
    split2_k<<<gW, blk256, 0, stream>>>(wproj[7], woh_d,           wol_d);
    split2_k<<<dim3(dictE / 8 / 256), blk256, 0, stream>>>(dict_e, dh, dl);

    build_x_k<<<gElem, blk256, 0, stream>>>(zL, qt, B0);

    // ---- layer attention block ----
    ln_split_k<<<dim3(NTOK / 4), blk256, 0, stream>>>(B0, gamma_l, beta_l, xh, xl);
    gemm_f16_k<0, false, false><<<gQKV, blk256, 0, stream>>>(xh, xl, qkvh_l, qkvl_l, nullptr, B1, QKVD);
    attn_l_k<<<dim3(128, NHEAD), blk256, 0, stream>>>(B1, xh, xl);
    gemm_f16_k<0, true, false><<<gWo, blk256, 0, stream>>>(xh, xl, woh_l, wol_l, nullptr, B0, HDIM);

    // ---- depth attention block ----
    ln_split_k<<<dim3(NTOK / 4), blk256, 0, stream>>>(B0, gamma_d, beta_d, xh, xl);
    gemm_f16_k<0, false, false><<<gQKV, blk256, 0, stream>>>(xh, xl, qkvh_d, qkvl_d, nullptr, B1, QKVD);
    attn_d_k<<<dim3(1024), blk128, 0, stream>>>(B1, xh, xl);
    gemm_f16_k<0, true, false><<<gWo, blk256, 0, stream>>>(xh, xl, woh_d, wol_d, nullptr, B0, HDIM);

    // ---- x_prior out + x_src split ----
    xprior_xsrc_k<<<gElem, blk256, 0, stream>>>(zL, bias_pre, B0, out_xp, xh, xl);

    for (int c0 = 0; c0 < NTOK; c0 += crows) {
        if ((crows & 127) == 0 && (crows / 128) * 64 % 8 == 0) {
            gemm_f16_k<1, false, true><<<dim3(64 * (crows / 128)), blk256, 0, stream>>>(
                xh + (size_t)c0 * HDIM, xl + (size_t)c0 * HDIM,
                dh, dl, bias_enc, logits, FDIM);
        } else {
            gemm_f16_k<0, false, true><<<dim3(FDIM / 64, crows / 128), blk256, 0, stream>>>(
                xh + (size_t)c0 * HDIM, xl + (size_t)c0 * HDIM,
                dh, dl, bias_enc, logits, FDIM);
        }
        topk_k<<<dim3(crows), blk256, 0, stream>>>(logits, out_z + (size_t)c0 * FDIM);
    }
}

// Round 19
// 991.434 us; speedup vs baseline: 1.2027x; 1.0764x over previous
//
#include <hip/hip_runtime.h>
#include <stdint.h>

#define NTOK 16384        // B*D*L = 8*16*128
#define HDIM 512
#define FDIM 4096
#define NHEAD 8
#define QKVD 1536         // fused QKV row width
#define L2E 1.44269504f   // log2(e)

typedef __attribute__((ext_vector_type(8))) _Float16 f16x8;
typedef __attribute__((ext_vector_type(16))) float f32x16;
#define LOSCALE 4096.0f
#define LOINV   (1.0f / 4096.0f)

static __device__ __forceinline__ void ld8f(const float* p, float* v) {
    *(float4*)&v[0] = *(const float4*)p;
    *(float4*)&v[4] = *(const float4*)(p + 4);
}
static __device__ __forceinline__ void st8f(float* p, const float* v) {
    *(float4*)p       = *(const float4*)&v[0];
    *(float4*)(p + 4) = *(const float4*)&v[4];
}
static __device__ __forceinline__ uint32_t packsplit(float v) {
    _Float16 h = (_Float16)v;
    _Float16 l = (_Float16)((v - (float)h) * LOSCALE);
    union { _Float16 f; uint16_t u; } ch{h}, cl{l};
    return (uint32_t)ch.u | ((uint32_t)cl.u << 16);
}
static __device__ __forceinline__ void unpack8(const uint32_t* p, f16x8* h, f16x8* l) {
    union { uint16_t s[8]; f16x8 v; } uh, ul;
#pragma unroll
    for (int i = 0; i < 8; ++i) {
        uint32_t x = p[i];
        uh.s[i] = (uint16_t)(x & 0xffffu);
        ul.s[i] = (uint16_t)(x >> 16);
    }
    *h = uh.v;
    *l = ul.v;
}

// ---- x0 = concat(query_token, zL[:, :-1]) -> f32 ----
__global__ __launch_bounds__(256) void build_x_k(const float* __restrict__ zL,
                                                 const float* __restrict__ qt,
                                                 float* __restrict__ X) {
    int idx = blockIdx.x * 256 + threadIdx.x;
    int n = idx >> 6;
    int h = (idx & 63) << 3;
    int d = (n >> 7) & 15;
    const float* src = d ? (zL + (((size_t)(n - 128)) << 9) + h) : (qt + h);
    float v[8];
    ld8f(src, v);
    st8f(X + (((size_t)n) << 9) + h, v);
}

// ---- fused LN stats + LN + fp16 2-way split (one wave per row) ----
__global__ __launch_bounds__(256) void ln_split_k(const float* __restrict__ X,
                                                  const float* __restrict__ gamma,
                                                  const float* __restrict__ beta,
                                                  _Float16* __restrict__ ph,
                                                  _Float16* __restrict__ pl) {
    int row = blockIdx.x * 4 + (threadIdx.x >> 6);
    int lane = threadIdx.x & 63;
    int h = lane << 3;
    const float* xr = X + (((size_t)row) << 9) + h;
    float v[8];
    ld8f(xr, v);
    float s = 0.f;
#pragma unroll
    for (int i = 0; i < 8; ++i) s += v[i];
#pragma unroll
    for (int off = 32; off; off >>= 1) s += __shfl_xor(s, off);
    float m = s * (1.0f / 512.0f);
    float q = 0.f;
#pragma unroll
    for (int i = 0; i < 8; ++i) { float d = v[i] - m; q += d * d; }
#pragma unroll
    for (int off = 32; off; off >>= 1) q += __shfl_xor(q, off);
    float rs = 1.0f / sqrtf(q * (1.0f / 512.0f) + 1e-5f);
    float gv[8], be[8];
    ld8f(gamma + h, gv);
    ld8f(beta + h, be);
    _Float16 h8[8], l8[8];
#pragma unroll
    for (int i = 0; i < 8; ++i) {
        float y = (v[i] - m) * rs * gv[i] + be[i];
        _Float16 hh = (_Float16)y;
        h8[i] = hh;
        l8[i] = (_Float16)((y - (float)hh) * LOSCALE);
    }
    size_t off = (((size_t)row) << 9) + h;
    *(int4*)(ph + off) = *(int4*)h8;
    *(int4*)(pl + off) = *(int4*)l8;
}

// ---- non-causal attention over L via split-fp16 MFMA flash block -----------
__global__ __launch_bounds__(256) void attn_l_k(const float* __restrict__ QKV,
                                                _Float16* __restrict__ xh,
                                                _Float16* __restrict__ xl) {
    __shared__ uint32_t pool[25024];
    uint32_t* Qp = pool;
    uint32_t* Kp = pool + 8320;
    uint32_t* Vt = pool + 16640;
    float*    rl = (float*)(pool + 24896);
    uint32_t* S  = pool;                 // phase 2+ (aliases Qp/Kp)

    const int seq = blockIdx.x, head = blockIdx.y;
    const int t = threadIdx.x;
    const size_t tok0 = (size_t)seq << 7;
    const int ho = head << 6;
    const int w = t >> 6, lane = t & 63;
    const int wr = w >> 1, wc = w & 1;
    const int l31 = lane & 31, hh = lane >> 5;

#pragma unroll
    for (int i = 0; i < 8; ++i) {
        int idx = t + (i << 8);
        int row = idx >> 4, c4 = (idx & 15) << 2;
        size_t g = (tok0 + row) * QKVD + ho + c4;
        float4 qv = *(const float4*)(QKV + g);
        float4 kv = *(const float4*)(QKV + g + 512);
        float4 vv = *(const float4*)(QKV + g + 1024);
        uint32_t* qd = Qp + row * 65 + c4;
        qd[0] = packsplit(qv.x); qd[1] = packsplit(qv.y);
        qd[2] = packsplit(qv.z); qd[3] = packsplit(qv.w);
        uint32_t* kd = Kp + row * 65 + c4;
        kd[0] = packsplit(kv.x); kd[1] = packsplit(kv.y);
        kd[2] = packsplit(kv.z); kd[3] = packsplit(kv.w);
        Vt[(c4 + 0) * 129 + row] = packsplit(vv.x);
        Vt[(c4 + 1) * 129 + row] = packsplit(vv.y);
        Vt[(c4 + 2) * 129 + row] = packsplit(vv.z);
        Vt[(c4 + 3) * 129 + row] = packsplit(vv.w);
    }
    __syncthreads();

    f32x16 a1[2][2], a2[2][2];
#pragma unroll
    for (int i = 0; i < 2; ++i)
#pragma unroll
        for (int j = 0; j < 2; ++j)
#pragma unroll
            for (int r = 0; r < 16; ++r) { a1[i][j][r] = 0.f; a2[i][j][r] = 0.f; }
#pragma unroll
    for (int ks = 0; ks < 4; ++ks) {
        const int ko = (ks << 4) + (hh << 3);
        f16x8 qh[2], ql[2], kh[2], kl[2];
#pragma unroll
        for (int mf = 0; mf < 2; ++mf)
            unpack8(Qp + ((wr << 6) + (mf << 5) + l31) * 65 + ko, &qh[mf], &ql[mf]);
#pragma unroll
        for (int nf = 0; nf < 2; ++nf)
            unpack8(Kp + ((wc << 6) + (nf << 5) + l31) * 65 + ko, &kh[nf], &kl[nf]);
#pragma unroll
        for (int nf = 0; nf < 2; ++nf)
#pragma unroll
            for (int mf = 0; mf < 2; ++mf) {
                a1[mf][nf] = __builtin_amdgcn_mfma_f32_32x32x16_f16(qh[mf], kh[nf], a1[mf][nf], 0, 0, 0);
                a2[mf][nf] = __builtin_amdgcn_mfma_f32_32x32x16_f16(qh[mf], kl[nf], a2[mf][nf], 0, 0, 0);
                a2[mf][nf] = __builtin_amdgcn_mfma_f32_32x32x16_f16(ql[mf], kh[nf], a2[mf][nf], 0, 0, 0);
            }
    }
    __syncthreads();
#pragma unroll
    for (int mf = 0; mf < 2; ++mf)
#pragma unroll
        for (int nf = 0; nf < 2; ++nf) {
            int col = (wc << 6) + (nf << 5) + l31;
#pragma unroll
            for (int r = 0; r < 16; ++r) {
                int row = (wr << 6) + (mf << 5) + (r & 3) + ((r >> 2) << 3) + (hh << 2);
                float sv = (a1[mf][nf][r] + a2[mf][nf][r] * LOINV) * 0.125f;
                S[row * 129 + col] = __float_as_uint(sv);
            }
        }
    __syncthreads();

    {
        int row = t >> 1, half = t & 1;
        uint32_t* sr = S + row * 129 + (half << 6);
        float mx = -1e30f;
#pragma unroll
        for (int j = 0; j < 64; ++j) mx = fmaxf(mx, __uint_as_float(sr[j]));
        mx = fmaxf(mx, __shfl_xor(mx, 1));
        float sum = 0.f;
#pragma unroll
        for (int j = 0; j < 64; ++j) {
            float wg = exp2f((__uint_as_float(sr[j]) - mx) * L2E);
            sum += wg;
            sr[j] = packsplit(wg);
        }
        sum += __shfl_xor(sum, 1);
        if (!half) rl[row] = 1.0f / sum;
    }
    __syncthreads();

    f32x16 o1[2], o2[2];
#pragma unroll
    for (int i = 0; i < 2; ++i)
#pragma unroll
        for (int r = 0; r < 16; ++r) { o1[i][r] = 0.f; o2[i][r] = 0.f; }
    const int dcol = (wc << 5) + l31;
#pragma unroll
    for (int ks = 0; ks < 8; ++ks) {
        const int jo = (ks << 4) + (hh << 3);
        f16x8 ph[2], pl2[2], vh, vl;
#pragma unroll
        for (int mf = 0; mf < 2; ++mf)
            unpack8(S + ((wr << 6) + (mf << 5) + l31) * 129 + jo, &ph[mf], &pl2[mf]);
        unpack8(Vt + dcol * 129 + jo, &vh, &vl);
#pragma unroll
        for (int mf = 0; mf < 2; ++mf) {
            o1[mf] = __builtin_amdgcn_mfma_f32_32x32x16_f16(ph[mf], vh, o1[mf], 0, 0, 0);
            o2[mf] = __builtin_amdgcn_mfma_f32_32x32x16_f16(ph[mf], vl, o2[mf], 0, 0, 0);
            o2[mf] = __builtin_amdgcn_mfma_f32_32x32x16_f16(pl2[mf], vh, o2[mf], 0, 0, 0);
        }
    }
#pragma unroll
    for (int mf = 0; mf < 2; ++mf)
#pragma unroll
        for (int r = 0; r < 16; ++r) {
            int row = (wr << 6) + (mf << 5) + (r & 3) + ((r >> 2) << 3) + (hh << 2);
            float y = (o1[mf][r] + o2[mf][r] * LOINV) * rl[row];
            size_t eo = ((tok0 + row) << 9) + ho + dcol;
            _Float16 hv = (_Float16)y;
            xh[eo] = hv;
            xl[eo] = (_Float16)((y - (float)hv) * LOSCALE);
        }
}

// ---- causal attention over D; per-head col rotation (bank-conflict-free) ---
__global__ __launch_bounds__(128) void attn_d_k(const float* __restrict__ QKV,
                                                _Float16* __restrict__ xh,
                                                _Float16* __restrict__ xl) {
    __shared__ float ks[16][512];
    __shared__ float vs[16][512];
    const int bl = blockIdx.x;
    const int b = bl >> 7, l = bl & 127;
    const int t = threadIdx.x;
    const size_t tok0 = (size_t)b * 2048 + l;
#pragma unroll
    for (int i = 0; i < 16; ++i) {
        int c4 = t << 2;
        int hc = c4 >> 6;
        int p  = (c4 & ~63) | ((c4 + (hc << 2)) & 63);
        size_t g = (tok0 + (size_t)i * 128) * QKVD + c4;
        *(float4*)&ks[i][p] = *(const float4*)(QKV + g + 512);
        *(float4*)&vs[i][p] = *(const float4*)(QKV + g + 1024);
    }
    __syncthreads();
    const int head = t >> 4, dr = t & 15;
    const int ho = head << 6;
    const int rot = head << 2;
    float qr[64];
    const float* qp = QKV + (tok0 + (size_t)dr * 128) * QKVD + ho;
#pragma unroll
    for (int i = 0; i < 16; ++i) *(float4*)&qr[i << 2] = *(const float4*)(qp + (i << 2));
    float s[16];
    float m = -1e30f;
#pragma unroll
    for (int j = 0; j < 16; ++j) {
        float s0 = 0.f, s1 = 0.f, s2 = 0.f, s3 = 0.f;
#pragma unroll
        for (int d = 0; d < 64; d += 4) {
            s0 = fmaf(qr[d + 0], ks[j][ho + ((d + 0 + rot) & 63)], s0);
            s1 = fmaf(qr[d + 1], ks[j][ho + ((d + 1 + rot) & 63)], s1);
            s2 = fmaf(qr[d + 2], ks[j][ho + ((d + 2 + rot) & 63)], s2);
            s3 = fmaf(qr[d + 3], ks[j][ho + ((d + 3 + rot) & 63)], s3);
        }
        float sv = ((s0 + s1) + (s2 + s3)) * 0.125f;
        s[j] = (j <= dr) ? sv : -1e30f;
        m = fmaxf(m, s[j]);
    }
    float lsum = 0.f;
#pragma unroll
    for (int j = 0; j < 16; ++j) {
        float w = (j <= dr) ? exp2f((s[j] - m) * L2E) : 0.f;
        s[j] = w;
        lsum += w;
    }
    float inv = 1.0f / lsum;
    float o[64];
#pragma unroll
    for (int d = 0; d < 64; ++d) o[d] = 0.f;
#pragma unroll
    for (int j = 0; j < 16; ++j) {
        float w = s[j];
#pragma unroll
        for (int d = 0; d < 64; ++d) o[d] = fmaf(w, vs[j][ho + ((d + rot) & 63)], o[d]);
    }
    size_t eo = ((tok0 + (size_t)dr * 128) << 9) + ho;
#pragma unroll
    for (int i = 0; i < 8; ++i) {
        _Float16 h8[8], l8[8];
#pragma unroll
        for (int j = 0; j < 8; ++j) {
            float y = o[i * 8 + j] * inv;
            _Float16 hh = (_Float16)y;
            h8[j] = hh;
            l8[j] = (_Float16)((y - (float)hh) * LOSCALE);
        }
        *(int4*)(xh + eo + (i << 3)) = *(int4*)h8;
        *(int4*)(xl + eo + (i << 3)) = *(int4*)l8;
    }
}

// ---- fused: out_xp = x; split(zL - x - bias_pre) -> xh/xl ----
__global__ __launch_bounds__(256) void xprior_xsrc_k(const float* __restrict__ zL,
                                                     const float* __restrict__ bias_pre,
                                                     const float* __restrict__ X,
                                                     float* __restrict__ out_xp,
                                                     _Float16* __restrict__ xh,
                                                     _Float16* __restrict__ xl) {
    int idx = blockIdx.x * 256 + threadIdx.x;
    int h = (idx & 63) << 3;
    size_t off = ((size_t)idx) << 3;
    float z[8], p[8], x[8];
    ld8f(zL + off, z);
    ld8f(bias_pre + h, p);
    ld8f(X + off, x);
    st8f(out_xp + off, x);
    _Float16 h8[8], l8[8];
#pragma unroll
    for (int i = 0; i < 8; ++i) {
        float y = z[i] - x[i] - p[i];
        _Float16 hh = (_Float16)y;
        h8[i] = hh;
        l8[i] = (_Float16)((y - (float)hh) * LOSCALE);
    }
    *(int4*)(xh + off) = *(int4*)h8;
    *(int4*)(xl + off) = *(int4*)l8;
}

// ---- 2-way fp16 scaled split: x = h + l*2^-12 ----
__global__ __launch_bounds__(256) void split2_k(const float* __restrict__ in,
                                                _Float16* __restrict__ ph,
                                                _Float16* __restrict__ pl) {
    int idx = blockIdx.x * 256 + threadIdx.x;
    float v[8];
    ld8f(in + (((size_t)idx) << 3), v);
    _Float16 h8[8], l8[8];
#pragma unroll
    for (int i = 0; i < 8; ++i) {
        _Float16 h = (_Float16)v[i];
        float r = v[i] - (float)h;          // exact
        h8[i] = h;
        l8[i] = (_Float16)(r * LOSCALE);
    }
    *(int4*)(ph + (((size_t)idx) << 3)) = *(int4*)h8;
    *(int4*)(pl + (((size_t)idx) << 3)) = *(int4*)l8;
}

// ---- batched weight split: all 8 projection matrices in one launch ----
// grid.x = 8 * (WE/8/256); weight w = blockIdx.x / perW
__global__ __launch_bounds__(256) void split2w_k(const float* __restrict__ w0,
                                                 const float* __restrict__ w1,
                                                 const float* __restrict__ w2,
                                                 const float* __restrict__ w3,
                                                 const float* __restrict__ w4,
                                                 const float* __restrict__ w5,
                                                 const float* __restrict__ w6,
                                                 const float* __restrict__ w7,
                                                 _Float16* __restrict__ dsth,  // 8 x WE, strided 2*WE? no: see launcher
                                                 _Float16* __restrict__ dstl,
                                                 int perW, int WEsz) {
    int wsel = blockIdx.x / perW;
    int bid  = blockIdx.x % perW;
    const float* src = wsel == 0 ? w0 : wsel == 1 ? w1 : wsel == 2 ? w2 : wsel == 3 ? w3
                    : wsel == 4 ? w4 : wsel == 5 ? w5 : wsel == 6 ? w6 : w7;
    int idx = bid * 256 + threadIdx.x;
    float v[8];
    ld8f(src + (((size_t)idx) << 3), v);
    _Float16 h8[8], l8[8];
#pragma unroll
    for (int i = 0; i < 8; ++i) {
        _Float16 h = (_Float16)v[i];
        float r = v[i] - (float)h;
        h8[i] = h;
        l8[i] = (_Float16)(r * LOSCALE);
    }
    size_t off = (size_t)wsel * WEsz + (((size_t)idx) << 3);
    *(int4*)(dsth + off) = *(int4*)h8;
    *(int4*)(dstl + off) = *(int4*)l8;
}

// ---- 3-pass split-fp16 MFMA NT GEMM, 32x32x16, 128x64 tile, 2-phase dbuf ---
#define LDT 34
template<int SWZ, bool ADD_C, bool BIAS>
__global__ __launch_bounds__(256) void gemm_f16_k(
        const _Float16* __restrict__ Xh, const _Float16* __restrict__ Xl,
        const _Float16* __restrict__ Wh, const _Float16* __restrict__ Wl,
        const float* __restrict__ bias, float* __restrict__ Cout, int ldc) {
    __shared__ _Float16 Ah[2][128][LDT], Al[2][128][LDT];
    __shared__ _Float16 Bh[2][64][LDT],  Bl[2][64][LDT];
    const int tid = threadIdx.x;
    int bm, bn;
    if (SWZ) {
        int id = blockIdx.x;
        int xcd = id & 7, ww = id >> 3;
        bn = ((xcd << 3) | (ww & 7)) << 6;
        bm = (ww >> 3) << 7;
    } else {
        bm = blockIdx.y << 7;
        bn = blockIdx.x << 6;
    }
    const int w = tid >> 6, lane = tid & 63;
    const int wr = w >> 1, wc = w & 1;
    const int l31 = lane & 31, hh = lane >> 5;
    const int ar0 = tid >> 2, akg = (tid & 3) << 3;
    const int ar1 = ar0 + 64;
    const _Float16* pXh0 = Xh + (size_t)(bm + ar0) * HDIM + akg;
    const _Float16* pXl0 = Xl + (size_t)(bm + ar0) * HDIM + akg;
    const _Float16* pXh1 = Xh + (size_t)(bm + ar1) * HDIM + akg;
    const _Float16* pXl1 = Xl + (size_t)(bm + ar1) * HDIM + akg;
    const _Float16* pWh  = Wh + (size_t)(bn + ar0) * HDIM + akg;
    const _Float16* pWl  = Wl + (size_t)(bn + ar0) * HDIM + akg;

    f32x16 acc1[2], acc2[2];
#pragma unroll
    for (int i = 0; i < 2; ++i)
#pragma unroll
        for (int r = 0; r < 16; ++r) { acc1[i][r] = 0.f; acc2[i][r] = 0.f; }

    int4 ra0h, ra0l, ra1h, ra1l, rbh, rbl;
    auto LOADR = [&](int k0) {
        ra0h = *(const int4*)(pXh0 + k0);
        ra0l = *(const int4*)(pXl0 + k0);
        ra1h = *(const int4*)(pXh1 + k0);
        ra1l = *(const int4*)(pXl1 + k0);
        rbh  = *(const int4*)(pWh + k0);
        rbl  = *(const int4*)(pWl + k0);
    };
    auto STORE = [&](int buf) {
        *(int4*)&Ah[buf][ar0][akg] = ra0h;
        *(int4*)&Al[buf][ar0][akg] = ra0l;
        *(int4*)&Ah[buf][ar1][akg] = ra1h;
        *(int4*)&Al[buf][ar1][akg] = ra1l;
        *(int4*)&Bh[buf][ar0][akg] = rbh;
        *(int4*)&Bl[buf][ar0][akg] = rbl;
    };

    LOADR(0);
    STORE(0);
    int cur = 0;
    for (int it = 0; it < 16; ++it) {
        if (it < 15) LOADR((it + 1) << 5);
        __syncthreads();
#pragma unroll
        for (int kh = 0; kh < 2; ++kh) {
            const int ko = (kh << 4) + (hh << 3);
            f16x8 fah[2], fal[2];
#pragma unroll
            for (int mf = 0; mf < 2; ++mf) {
                int ar = (wr << 6) + (mf << 5) + l31;
                fah[mf] = *(const f16x8*)&Ah[cur][ar][ko];
                fal[mf] = *(const f16x8*)&Al[cur][ar][ko];
            }
            int bc_ = (wc << 5) + l31;
            f16x8 bh = *(const f16x8*)&Bh[cur][bc_][ko];
            f16x8 bl = *(const f16x8*)&Bl[cur][bc_][ko];
#pragma unroll
            for (int mf = 0; mf < 2; ++mf) {
                acc1[mf] = __builtin_amdgcn_mfma_f32_32x32x16_f16(fah[mf], bh, acc1[mf], 0, 0, 0);
                acc2[mf] = __builtin_amdgcn_mfma_f32_32x32x16_f16(fah[mf], bl, acc2[mf], 0, 0, 0);
                acc2[mf] = __builtin_amdgcn_mfma_f32_32x32x16_f16(fal[mf], bh, acc2[mf], 0, 0, 0);
            }
        }
        if (it < 15) { STORE(cur ^ 1); cur ^= 1; }
    }
    const int col = bn + (wc << 5) + l31;
    const float badd = BIAS ? bias[col] : 0.f;
#pragma unroll
    for (int mf = 0; mf < 2; ++mf) {
#pragma unroll
        for (int r = 0; r < 16; ++r) {
            int row = bm + (wr << 6) + (mf << 5) + (r & 3) + ((r >> 2) << 3) + (hh << 2);
            float* cp = Cout + (size_t)row * ldc + col;
            float val = acc1[mf][r] + acc2[mf][r] * LOINV + badd;
            if (ADD_C) val += *cp;
            *cp = val;
        }
    }
}

// ---- per-row top-64: relu + exact radix select (early-exit, 1 barrier/iter) -
__global__ __launch_bounds__(256) void topk_k(const float* __restrict__ logits,
                                              float* __restrict__ out) {
    const int row = blockIdx.x;
    const float* lr = logits + (((size_t)row) << 12);
    const int t = threadIdx.x;
    float v[16]; uint32_t u[16];
#pragma unroll
    for (int i = 0; i < 16; ++i) {
        float x = fmaxf(lr[t + (i << 8)], 0.f);
        v[i] = x;
        u[i] = __float_as_uint(x);
    }
    __shared__ int red[2][4];            // parity-buffered -> 1 barrier per iter
    __shared__ unsigned long long bits[64];
    __shared__ int s_cut;
    uint32_t prefix = 0;
    bool exact = false;
    int par = 0;
    for (int bit = 30; bit >= 0; --bit, par ^= 1) {
        uint32_t c = prefix | (1u << bit);
        int cnt = 0;
#pragma unroll
        for (int i = 0; i < 16; ++i) cnt += (u[i] >= c) ? 1 : 0;
#pragma unroll
        for (int off = 32; off; off >>= 1) cnt += __shfl_xor(cnt, off);
        if ((t & 63) == 0) red[par][t >> 6] = cnt;
        __syncthreads();
        int total = red[par][0] + red[par][1] + red[par][2] + red[par][3];
        if (total >= 64) prefix = c;
        if (total == 64) { exact = true; break; }
    }
    float* orow = out + (((size_t)row) << 12);
    if (exact) {
#pragma unroll
        for (int i = 0; i < 16; ++i) {
            int col = t + (i << 8);
            orow[col] = (u[i] >= prefix) ? v[i] : 0.f;
        }
        return;
    }
    const uint32_t T64 = prefix;
    int cg = 0;
#pragma unroll
    for (int i = 0; i < 16; ++i) cg += (u[i] > T64) ? 1 : 0;
#pragma unroll
    for (int off = 32; off; off >>= 1) cg += __shfl_xor(cg, off);
    __syncthreads();                     // protect red[par] before rewrite
    if ((t & 63) == 0) red[0][t >> 6] = cg;
    __syncthreads();
    const int ngt = red[0][0] + red[0][1] + red[0][2] + red[0][3];
    int cut = -1;
    if (T64 != 0u) {
        const int r = 64 - ngt;
        if (t < 64) bits[t] = 0ull;
        __syncthreads();
#pragma unroll
        for (int i = 0; i < 16; ++i) {
            if (u[i] == T64) {
                int col = t + (i << 8);
                atomicOr(&bits[col >> 6], 1ull << (col & 63));
            }
        }
        __syncthreads();
        if (t == 0) {
            int need = r, cs = FDIM - 1;
            for (int wd = 0; wd < 64; ++wd) {
                int pc = __popcll(bits[wd]);
                if (need <= pc) {
                    unsigned long long bb = bits[wd];
                    for (int q = 1; q < need; ++q) bb &= bb - 1;
                    cs = (wd << 6) + (__ffsll(bb) - 1);
                    break;
                }
                need -= pc;
            }
            s_cut = cs;
        }
        __syncthreads();
        cut = s_cut;
    }
#pragma unroll
    for (int i = 0; i < 16; ++i) {
        int col = t + (i << 8);
        bool keep = (u[i] > T64) || (T64 != 0u && u[i] == T64 && col <= cut);
        orow[col] = keep ? v[i] : 0.f;
    }
}

extern "C" void kernel_launch(void* const* d_in, const int* in_sizes, int n_in,
                              void* d_out, int out_size, void* d_ws, size_t ws_size,
                              hipStream_t stream) {
    const float* zL      = (const float*)d_in[0];
    const float* gamma_l = (const float*)d_in[5];
    const float* beta_l  = (const float*)d_in[6];
    const float* gamma_d = (const float*)d_in[11];
    const float* beta_d  = (const float*)d_in[12];
    const float* dict_e  = (const float*)d_in[13];
    const float* bias_pre= (const float*)d_in[14];
    const float* bias_enc= (const float*)d_in[15];
    const float* qt      = (const float*)d_in[16];
    // weight order in ws: [qkv_l 3][wo_l][qkv_d 3][wo_d]
    const float* worder[8] = { (const float*)d_in[1], (const float*)d_in[2],
                               (const float*)d_in[3], (const float*)d_in[4],
                               (const float*)d_in[7], (const float*)d_in[8],
                               (const float*)d_in[9], (const float*)d_in[10] };

    float* out_z  = (float*)d_out;
    float* out_xp = out_z + (size_t)NTOK * FDIM;

    const size_t NHf = (size_t)NTOK * HDIM;
    float* B0 = (float*)d_out;         // residual X (z_n region)
    float* B1 = B0 + NHf;              // fused QKV [16384][1536]

    float* wsf    = (float*)d_ws;
    float* logits = wsf + 64;

    const size_t dictE = (size_t)FDIM * HDIM;
    const size_t WE    = (size_t)HDIM * HDIM;

    int crows = 4096;                  // 67 MB logits chunk (L3-resident)
    const size_t fixedB = 64 * sizeof(float)
                        + (2 * dictE + 16 * WE + 2 * NHf) * sizeof(_Float16);
    while (crows > 128 && fixedB + (size_t)crows * FDIM * sizeof(float) > ws_size)
        crows >>= 1;

    _Float16* dh  = (_Float16*)(logits + (size_t)crows * FDIM);
    _Float16* dl  = dh + dictE;
    _Float16* wsph = dh + 2 * dictE;   // 8 x WE (h), then 8 x WE (l)
    _Float16* wspl = wsph + 8 * WE;
    _Float16* xh  = wspl + 8 * WE;
    _Float16* xl  = xh + NHf;
    // layer L: qkv at wsph[0..3WE), wo at wsph[3WE..4WE); layer D at +4WE
    _Float16* qkvh_l = wsph;
    _Float16* qkvl_l = wspl;
    _Float16* woh_l  = wsph + 3 * WE;
    _Float16* wol_l  = wspl + 3 * WE;
    _Float16* qkvh_d = wsph + 4 * WE;
    _Float16* qkvl_d = wspl + 4 * WE;
    _Float16* woh_d  = wsph + 7 * WE;
    _Float16* wol_d  = wspl + 7 * WE;

    const dim3 blk256(256), blk128(128);
    const dim3 gElem(4096);
    const int perW = (int)(WE / 8 / 256);
    const dim3 gQKV(QKVD / 64, NTOK / 128);
    const dim3 gWo(HDIM / 64, NTOK / 128);

    split2w_k<<<dim3(8 * perW), blk256, 0, stream>>>(
        worder[0], worder[1], worder[2], worder[3],
        worder[4], worder[5], worder[6], worder[7],
        wsph, wspl, perW, (int)WE);
    split2_k<<<dim3(dictE / 8 / 256), blk256, 0, stream>>>(dict_e, dh, dl);

    build_x_k<<<gElem, blk256, 0, stream>>>(zL, qt, B0);

    // ---- layer attention block ----
    ln_split_k<<<dim3(NTOK / 4), blk256, 0, stream>>>(B0, gamma_l, beta_l, xh, xl);
    gemm_f16_k<0, false, false><<<gQKV, blk256, 0, stream>>>(xh, xl, qkvh_l, qkvl_l, nullptr, B1, QKVD);
    attn_l_k<<<dim3(128, NHEAD), blk256, 0, stream>>>(B1, xh, xl);
    gemm_f16_k<0, true, false><<<gWo, blk256, 0, stream>>>(xh, xl, woh_l, wol_l, nullptr, B0, HDIM);

    // ---- depth attention block ----
    ln_split_k<<<dim3(NTOK / 4), blk256, 0, stream>>>(B0, gamma_d, beta_d, xh, xl);
    gemm_f16_k<0, false, false><<<gQKV, blk256, 0, stream>>>(xh, xl, qkvh_d, qkvl_d, nullptr, B1, QKVD);
    attn_d_k<<<dim3(1024), blk128, 0, stream>>>(B1, xh, xl);
    gemm_f16_k<0, true, false><<<gWo, blk256, 0, stream>>>(xh, xl, woh_d, wol_d, nullptr, B0, HDIM);

    // ---- x_prior out + x_src split ----
    xprior_xsrc_k<<<gElem, blk256, 0, stream>>>(zL, bias_pre, B0, out_xp, xh, xl);

    for (int c0 = 0; c0 < NTOK; c0 += crows) {
        if ((crows & 127) == 0 && (crows / 128) * 64 % 8 == 0) {
            gemm_f16_k<1, false, true><<<dim3(64 * (crows / 128)), blk256, 0, stream>>>(
                xh + (size_t)c0 * HDIM, xl + (size_t)c0 * HDIM,
                dh, dl, bias_enc, logits, FDIM);
        } else {
            gemm_f16_k<0, false, true><<<dim3(FDIM / 64, crows / 128), blk256, 0, stream>>>(
                xh + (size_t)c0 * HDIM, xl + (size_t)c0 * HDIM,
                dh, dl, bias_enc, logits, FDIM);
        }
        topk_k<<<dim3(crows), blk256, 0, stream>>>(logits, out_z + (size_t)c0 * FDIM);
    }
}

// Round 20
// 986.096 us; speedup vs baseline: 1.2092x; 1.0054x over previous
//
#include <hip/hip_runtime.h>
#include <stdint.h>

#define NTOK 16384        // B*D*L = 8*16*128
#define HDIM 512
#define FDIM 4096
#define NHEAD 8
#define QKVD 1536         // fused QKV row width
#define L2E 1.44269504f   // log2(e)

typedef __attribute__((ext_vector_type(8))) _Float16 f16x8;
typedef __attribute__((ext_vector_type(16))) float f32x16;
#define LOSCALE 4096.0f
#define LOINV   (1.0f / 4096.0f)

static __device__ __forceinline__ void ld8f(const float* p, float* v) {
    *(float4*)&v[0] = *(const float4*)p;
    *(float4*)&v[4] = *(const float4*)(p + 4);
}
static __device__ __forceinline__ void st8f(float* p, const float* v) {
    *(float4*)p       = *(const float4*)&v[0];
    *(float4*)(p + 4) = *(const float4*)&v[4];
}
static __device__ __forceinline__ uint32_t packsplit(float v) {
    _Float16 h = (_Float16)v;
    _Float16 l = (_Float16)((v - (float)h) * LOSCALE);
    union { _Float16 f; uint16_t u; } ch{h}, cl{l};
    return (uint32_t)ch.u | ((uint32_t)cl.u << 16);
}
static __device__ __forceinline__ void unpack8(const uint32_t* p, f16x8* h, f16x8* l) {
    union { uint16_t s[8]; f16x8 v; } uh, ul;
#pragma unroll
    for (int i = 0; i < 8; ++i) {
        uint32_t x = p[i];
        uh.s[i] = (uint16_t)(x & 0xffffu);
        ul.s[i] = (uint16_t)(x >> 16);
    }
    *h = uh.v;
    *l = ul.v;
}

// ---- fused: x0 = concat(qt, zL[:-1]) -> B0; LN; fp16 split -> xh/xl --------
__global__ __launch_bounds__(256) void ln_split_first_k(const float* __restrict__ zL,
                                                        const float* __restrict__ qt,
                                                        const float* __restrict__ gamma,
                                                        const float* __restrict__ beta,
                                                        float* __restrict__ X,
                                                        _Float16* __restrict__ ph,
                                                        _Float16* __restrict__ pl) {
    int row = blockIdx.x * 4 + (threadIdx.x >> 6);
    int lane = threadIdx.x & 63;
    int h = lane << 3;
    int d = (row >> 7) & 15;
    const float* sr = d ? (zL + (((size_t)(row - 128)) << 9) + h) : (qt + h);
    float v[8];
    ld8f(sr, v);
    st8f(X + (((size_t)row) << 9) + h, v);    // residual copy
    float s = 0.f;
#pragma unroll
    for (int i = 0; i < 8; ++i) s += v[i];
#pragma unroll
    for (int off = 32; off; off >>= 1) s += __shfl_xor(s, off);
    float m = s * (1.0f / 512.0f);
    float q = 0.f;
#pragma unroll
    for (int i = 0; i < 8; ++i) { float dd = v[i] - m; q += dd * dd; }
#pragma unroll
    for (int off = 32; off; off >>= 1) q += __shfl_xor(q, off);
    float rs = 1.0f / sqrtf(q * (1.0f / 512.0f) + 1e-5f);
    float gv[8], be[8];
    ld8f(gamma + h, gv);
    ld8f(beta + h, be);
    _Float16 h8[8], l8[8];
#pragma unroll
    for (int i = 0; i < 8; ++i) {
        float y = (v[i] - m) * rs * gv[i] + be[i];
        _Float16 hh = (_Float16)y;
        h8[i] = hh;
        l8[i] = (_Float16)((y - (float)hh) * LOSCALE);
    }
    size_t off = (((size_t)row) << 9) + h;
    *(int4*)(ph + off) = *(int4*)h8;
    *(int4*)(pl + off) = *(int4*)l8;
}

// ---- fused LN stats + LN + fp16 2-way split (one wave per row) ----
__global__ __launch_bounds__(256) void ln_split_k(const float* __restrict__ X,
                                                  const float* __restrict__ gamma,
                                                  const float* __restrict__ beta,
                                                  _Float16* __restrict__ ph,
                                                  _Float16* __restrict__ pl) {
    int row = blockIdx.x * 4 + (threadIdx.x >> 6);
    int lane = threadIdx.x & 63;
    int h = lane << 3;
    const float* xr = X + (((size_t)row) << 9) + h;
    float v[8];
    ld8f(xr, v);
    float s = 0.f;
#pragma unroll
    for (int i = 0; i < 8; ++i) s += v[i];
#pragma unroll
    for (int off = 32; off; off >>= 1) s += __shfl_xor(s, off);
    float m = s * (1.0f / 512.0f);
    float q = 0.f;
#pragma unroll
    for (int i = 0; i < 8; ++i) { float d = v[i] - m; q += d * d; }
#pragma unroll
    for (int off = 32; off; off >>= 1) q += __shfl_xor(q, off);
    float rs = 1.0f / sqrtf(q * (1.0f / 512.0f) + 1e-5f);
    float gv[8], be[8];
    ld8f(gamma + h, gv);
    ld8f(beta + h, be);
    _Float16 h8[8], l8[8];
#pragma unroll
    for (int i = 0; i < 8; ++i) {
        float y = (v[i] - m) * rs * gv[i] + be[i];
        _Float16 hh = (_Float16)y;
        h8[i] = hh;
        l8[i] = (_Float16)((y - (float)hh) * LOSCALE);
    }
    size_t off = (((size_t)row) << 9) + h;
    *(int4*)(ph + off) = *(int4*)h8;
    *(int4*)(pl + off) = *(int4*)l8;
}

// ---- non-causal attention over L via split-fp16 MFMA flash block -----------
__global__ __launch_bounds__(256) void attn_l_k(const float* __restrict__ QKV,
                                                _Float16* __restrict__ xh,
                                                _Float16* __restrict__ xl) {
    __shared__ uint32_t pool[25024];
    uint32_t* Qp = pool;
    uint32_t* Kp = pool + 8320;
    uint32_t* Vt = pool + 16640;
    float*    rl = (float*)(pool + 24896);
    uint32_t* S  = pool;                 // phase 2+ (aliases Qp/Kp)

    const int seq = blockIdx.x, head = blockIdx.y;
    const int t = threadIdx.x;
    const size_t tok0 = (size_t)seq << 7;
    const int ho = head << 6;
    const int w = t >> 6, lane = t & 63;
    const int wr = w >> 1, wc = w & 1;
    const int l31 = lane & 31, hh = lane >> 5;

#pragma unroll
    for (int i = 0; i < 8; ++i) {
        int idx = t + (i << 8);
        int row = idx >> 4, c4 = (idx & 15) << 2;
        size_t g = (tok0 + row) * QKVD + ho + c4;
        float4 qv = *(const float4*)(QKV + g);
        float4 kv = *(const float4*)(QKV + g + 512);
        float4 vv = *(const float4*)(QKV + g + 1024);
        uint32_t* qd = Qp + row * 65 + c4;
        qd[0] = packsplit(qv.x); qd[1] = packsplit(qv.y);
        qd[2] = packsplit(qv.z); qd[3] = packsplit(qv.w);
        uint32_t* kd = Kp + row * 65 + c4;
        kd[0] = packsplit(kv.x); kd[1] = packsplit(kv.y);
        kd[2] = packsplit(kv.z); kd[3] = packsplit(kv.w);
        Vt[(c4 + 0) * 129 + row] = packsplit(vv.x);
        Vt[(c4 + 1) * 129 + row] = packsplit(vv.y);
        Vt[(c4 + 2) * 129 + row] = packsplit(vv.z);
        Vt[(c4 + 3) * 129 + row] = packsplit(vv.w);
    }
    __syncthreads();

    f32x16 a1[2][2], a2[2][2];
#pragma unroll
    for (int i = 0; i < 2; ++i)
#pragma unroll
        for (int j = 0; j < 2; ++j)
#pragma unroll
            for (int r = 0; r < 16; ++r) { a1[i][j][r] = 0.f; a2[i][j][r] = 0.f; }
#pragma unroll
    for (int ks = 0; ks < 4; ++ks) {
        const int ko = (ks << 4) + (hh << 3);
        f16x8 qh[2], ql[2], kh[2], kl[2];
#pragma unroll
        for (int mf = 0; mf < 2; ++mf)
            unpack8(Qp + ((wr << 6) + (mf << 5) + l31) * 65 + ko, &qh[mf], &ql[mf]);
#pragma unroll
        for (int nf = 0; nf < 2; ++nf)
            unpack8(Kp + ((wc << 6) + (nf << 5) + l31) * 65 + ko, &kh[nf], &kl[nf]);
#pragma unroll
        for (int nf = 0; nf < 2; ++nf)
#pragma unroll
            for (int mf = 0; mf < 2; ++mf) {
                a1[mf][nf] = __builtin_amdgcn_mfma_f32_32x32x16_f16(qh[mf], kh[nf], a1[mf][nf], 0, 0, 0);
                a2[mf][nf] = __builtin_amdgcn_mfma_f32_32x32x16_f16(qh[mf], kl[nf], a2[mf][nf], 0, 0, 0);
                a2[mf][nf] = __builtin_amdgcn_mfma_f32_32x32x16_f16(ql[mf], kh[nf], a2[mf][nf], 0, 0, 0);
            }
    }
    __syncthreads();
#pragma unroll
    for (int mf = 0; mf < 2; ++mf)
#pragma unroll
        for (int nf = 0; nf < 2; ++nf) {
            int col = (wc << 6) + (nf << 5) + l31;
#pragma unroll
            for (int r = 0; r < 16; ++r) {
                int row = (wr << 6) + (mf << 5) + (r & 3) + ((r >> 2) << 3) + (hh << 2);
                float sv = (a1[mf][nf][r] + a2[mf][nf][r] * LOINV) * 0.125f;
                S[row * 129 + col] = __float_as_uint(sv);
            }
        }
    __syncthreads();

    {
        int row = t >> 1, half = t & 1;
        uint32_t* sr = S + row * 129 + (half << 6);
        float mx = -1e30f;
#pragma unroll
        for (int j = 0; j < 64; ++j) mx = fmaxf(mx, __uint_as_float(sr[j]));
        mx = fmaxf(mx, __shfl_xor(mx, 1));
        float sum = 0.f;
#pragma unroll
        for (int j = 0; j < 64; ++j) {
            float wg = exp2f((__uint_as_float(sr[j]) - mx) * L2E);
            sum += wg;
            sr[j] = packsplit(wg);
        }
        sum += __shfl_xor(sum, 1);
        if (!half) rl[row] = 1.0f / sum;
    }
    __syncthreads();

    f32x16 o1[2], o2[2];
#pragma unroll
    for (int i = 0; i < 2; ++i)
#pragma unroll
        for (int r = 0; r < 16; ++r) { o1[i][r] = 0.f; o2[i][r] = 0.f; }
    const int dcol = (wc << 5) + l31;
#pragma unroll
    for (int ks = 0; ks < 8; ++ks) {
        const int jo = (ks << 4) + (hh << 3);
        f16x8 ph[2], pl2[2], vh, vl;
#pragma unroll
        for (int mf = 0; mf < 2; ++mf)
            unpack8(S + ((wr << 6) + (mf << 5) + l31) * 129 + jo, &ph[mf], &pl2[mf]);
        unpack8(Vt + dcol * 129 + jo, &vh, &vl);
#pragma unroll
        for (int mf = 0; mf < 2; ++mf) {
            o1[mf] = __builtin_amdgcn_mfma_f32_32x32x16_f16(ph[mf], vh, o1[mf], 0, 0, 0);
            o2[mf] = __builtin_amdgcn_mfma_f32_32x32x16_f16(ph[mf], vl, o2[mf], 0, 0, 0);
            o2[mf] = __builtin_amdgcn_mfma_f32_32x32x16_f16(pl2[mf], vh, o2[mf], 0, 0, 0);
        }
    }
#pragma unroll
    for (int mf = 0; mf < 2; ++mf)
#pragma unroll
        for (int r = 0; r < 16; ++r) {
            int row = (wr << 6) + (mf << 5) + (r & 3) + ((r >> 2) << 3) + (hh << 2);
            float y = (o1[mf][r] + o2[mf][r] * LOINV) * rl[row];
            size_t eo = ((tok0 + row) << 9) + ho + dcol;
            _Float16 hv = (_Float16)y;
            xh[eo] = hv;
            xl[eo] = (_Float16)((y - (float)hv) * LOSCALE);
        }
}

// ---- causal attention over D; 256 thr, 2 lanes per (head,row) unit ---------
// d-split 32/32 + shfl combine; rotation layout kept (2-way max = free).
__global__ __launch_bounds__(256) void attn_d_k(const float* __restrict__ QKV,
                                                _Float16* __restrict__ xh,
                                                _Float16* __restrict__ xl) {
    __shared__ float ks[16][512];
    __shared__ float vs[16][512];
    const int bl = blockIdx.x;
    const int b = bl >> 7, l = bl & 127;
    const int t = threadIdx.x;
    const size_t tok0 = (size_t)b * 2048 + l;
#pragma unroll
    for (int i = 0; i < 8; ++i) {
        int idx = t + (i << 8);
        int row = idx >> 7;
        int c4 = (idx & 127) << 2;
        int hc = c4 >> 6;
        int p  = (c4 & ~63) | ((c4 + (hc << 2)) & 63);
        size_t g = (tok0 + (size_t)row * 128) * QKVD + c4;
        *(float4*)&ks[row][p] = *(const float4*)(QKV + g + 512);
        *(float4*)&vs[row][p] = *(const float4*)(QKV + g + 1024);
    }
    __syncthreads();
    const int unit = t >> 1, sub = t & 1;
    const int head = unit >> 4, dr = unit & 15;
    const int ho = head << 6;
    const int rot = head << 2;
    const int d0 = sub << 5;            // this lane's 32-dim half
    float qr[32];
    const float* qp = QKV + (tok0 + (size_t)dr * 128) * QKVD + ho + d0;
#pragma unroll
    for (int i = 0; i < 8; ++i) *(float4*)&qr[i << 2] = *(const float4*)(qp + (i << 2));
    float s[16];
    float m = -1e30f;
#pragma unroll
    for (int j = 0; j < 16; ++j) {
        float s0 = 0.f, s1 = 0.f, s2 = 0.f, s3 = 0.f;
#pragma unroll
        for (int d = 0; d < 32; d += 4) {
            s0 = fmaf(qr[d + 0], ks[j][ho + ((d0 + d + 0 + rot) & 63)], s0);
            s1 = fmaf(qr[d + 1], ks[j][ho + ((d0 + d + 1 + rot) & 63)], s1);
            s2 = fmaf(qr[d + 2], ks[j][ho + ((d0 + d + 2 + rot) & 63)], s2);
            s3 = fmaf(qr[d + 3], ks[j][ho + ((d0 + d + 3 + rot) & 63)], s3);
        }
        float sp = (s0 + s1) + (s2 + s3);
        sp += __shfl_xor(sp, 1);        // combine d-halves
        float sv = sp * 0.125f;
        s[j] = (j <= dr) ? sv : -1e30f;
        m = fmaxf(m, s[j]);
    }
    float lsum = 0.f;
#pragma unroll
    for (int j = 0; j < 16; ++j) {
        float w = (j <= dr) ? exp2f((s[j] - m) * L2E) : 0.f;
        s[j] = w;
        lsum += w;
    }
    float inv = 1.0f / lsum;
    float o[32];
#pragma unroll
    for (int d = 0; d < 32; ++d) o[d] = 0.f;
#pragma unroll
    for (int j = 0; j < 16; ++j) {
        float w = s[j];
#pragma unroll
        for (int d = 0; d < 32; ++d) o[d] = fmaf(w, vs[j][ho + ((d0 + d + rot) & 63)], o[d]);
    }
    size_t eo = ((tok0 + (size_t)dr * 128) << 9) + ho + d0;
#pragma unroll
    for (int i = 0; i < 4; ++i) {
        _Float16 h8[8], l8[8];
#pragma unroll
        for (int j = 0; j < 8; ++j) {
            float y = o[i * 8 + j] * inv;
            _Float16 hh = (_Float16)y;
            h8[j] = hh;
            l8[j] = (_Float16)((y - (float)hh) * LOSCALE);
        }
        *(int4*)(xh + eo + (i << 3)) = *(int4*)h8;
        *(int4*)(xl + eo + (i << 3)) = *(int4*)l8;
    }
}

// ---- fused: out_xp = x; split(zL - x - bias_pre) -> xh/xl ----
__global__ __launch_bounds__(256) void xprior_xsrc_k(const float* __restrict__ zL,
                                                     const float* __restrict__ bias_pre,
                                                     const float* __restrict__ X,
                                                     float* __restrict__ out_xp,
                                                     _Float16* __restrict__ xh,
                                                     _Float16* __restrict__ xl) {
    int idx = blockIdx.x * 256 + threadIdx.x;
    int h = (idx & 63) << 3;
    size_t off = ((size_t)idx) << 3;
    float z[8], p[8], x[8];
    ld8f(zL + off, z);
    ld8f(bias_pre + h, p);
    ld8f(X + off, x);
    st8f(out_xp + off, x);
    _Float16 h8[8], l8[8];
#pragma unroll
    for (int i = 0; i < 8; ++i) {
        float y = z[i] - x[i] - p[i];
        _Float16 hh = (_Float16)y;
        h8[i] = hh;
        l8[i] = (_Float16)((y - (float)hh) * LOSCALE);
    }
    *(int4*)(xh + off) = *(int4*)h8;
    *(int4*)(xl + off) = *(int4*)l8;
}

// ---- 2-way fp16 scaled split: x = h + l*2^-12 ----
__global__ __launch_bounds__(256) void split2_k(const float* __restrict__ in,
                                                _Float16* __restrict__ ph,
                                                _Float16* __restrict__ pl) {
    int idx = blockIdx.x * 256 + threadIdx.x;
    float v[8];
    ld8f(in + (((size_t)idx) << 3), v);
    _Float16 h8[8], l8[8];
#pragma unroll
    for (int i = 0; i < 8; ++i) {
        _Float16 h = (_Float16)v[i];
        float r = v[i] - (float)h;          // exact
        h8[i] = h;
        l8[i] = (_Float16)(r * LOSCALE);
    }
    *(int4*)(ph + (((size_t)idx) << 3)) = *(int4*)h8;
    *(int4*)(pl + (((size_t)idx) << 3)) = *(int4*)l8;
}

// ---- batched weight split: all 8 projection matrices in one launch ----
__global__ __launch_bounds__(256) void split2w_k(const float* __restrict__ w0,
                                                 const float* __restrict__ w1,
                                                 const float* __restrict__ w2,
                                                 const float* __restrict__ w3,
                                                 const float* __restrict__ w4,
                                                 const float* __restrict__ w5,
                                                 const float* __restrict__ w6,
                                                 const float* __restrict__ w7,
                                                 _Float16* __restrict__ dsth,
                                                 _Float16* __restrict__ dstl,
                                                 int perW, int WEsz) {
    int wsel = blockIdx.x / perW;
    int bid  = blockIdx.x % perW;
    const float* src = wsel == 0 ? w0 : wsel == 1 ? w1 : wsel == 2 ? w2 : wsel == 3 ? w3
                    : wsel == 4 ? w4 : wsel == 5 ? w5 : wsel == 6 ? w6 : w7;
    int idx = bid * 256 + threadIdx.x;
    float v[8];
    ld8f(src + (((size_t)idx) << 3), v);
    _Float16 h8[8], l8[8];
#pragma unroll
    for (int i = 0; i < 8; ++i) {
        _Float16 h = (_Float16)v[i];
        float r = v[i] - (float)h;
        h8[i] = h;
        l8[i] = (_Float16)(r * LOSCALE);
    }
    size_t off = (size_t)wsel * WEsz + (((size_t)idx) << 3);
    *(int4*)(dsth + off) = *(int4*)h8;
    *(int4*)(dstl + off) = *(int4*)l8;
}

// ---- 3-pass split-fp16 MFMA NT GEMM, 32x32x16, 128x64 tile, 2-phase dbuf ---
#define LDT 34
template<int SWZ, bool ADD_C, bool BIAS>
__global__ __launch_bounds__(256) void gemm_f16_k(
        const _Float16* __restrict__ Xh, const _Float16* __restrict__ Xl,
        const _Float16* __restrict__ Wh, const _Float16* __restrict__ Wl,
        const float* __restrict__ bias, float* __restrict__ Cout, int ldc) {
    __shared__ _Float16 Ah[2][128][LDT], Al[2][128][LDT];
    __shared__ _Float16 Bh[2][64][LDT],  Bl[2][64][LDT];
    const int tid = threadIdx.x;
    int bm, bn;
    if (SWZ) {
        int id = blockIdx.x;
        int xcd = id & 7, ww = id >> 3;
        bn = ((xcd << 3) | (ww & 7)) << 6;
        bm = (ww >> 3) << 7;
    } else {
        bm = blockIdx.y << 7;
        bn = blockIdx.x << 6;
    }
    const int w = tid >> 6, lane = tid & 63;
    const int wr = w >> 1, wc = w & 1;
    const int l31 = lane & 31, hh = lane >> 5;
    const int ar0 = tid >> 2, akg = (tid & 3) << 3;
    const int ar1 = ar0 + 64;
    const _Float16* pXh0 = Xh + (size_t)(bm + ar0) * HDIM + akg;
    const _Float16* pXl0 = Xl + (size_t)(bm + ar0) * HDIM + akg;
    const _Float16* pXh1 = Xh + (size_t)(bm + ar1) * HDIM + akg;
    const _Float16* pXl1 = Xl + (size_t)(bm + ar1) * HDIM + akg;
    const _Float16* pWh  = Wh + (size_t)(bn + ar0) * HDIM + akg;
    const _Float16* pWl  = Wl + (size_t)(bn + ar0) * HDIM + akg;

    f32x16 acc1[2], acc2[2];
#pragma unroll
    for (int i = 0; i < 2; ++i)
#pragma unroll
        for (int r = 0; r < 16; ++r) { acc1[i][r] = 0.f; acc2[i][r] = 0.f; }

    int4 ra0h, ra0l, ra1h, ra1l, rbh, rbl;
    auto LOADR = [&](int k0) {
        ra0h = *(const int4*)(pXh0 + k0);
        ra0l = *(const int4*)(pXl0 + k0);
        ra1h = *(const int4*)(pXh1 + k0);
        ra1l = *(const int4*)(pXl1 + k0);
        rbh  = *(const int4*)(pWh + k0);
        rbl  = *(const int4*)(pWl + k0);
    };
    auto STORE = [&](int buf) {
        *(int4*)&Ah[buf][ar0][akg] = ra0h;
        *(int4*)&Al[buf][ar0][akg] = ra0l;
        *(int4*)&Ah[buf][ar1][akg] = ra1h;
        *(int4*)&Al[buf][ar1][akg] = ra1l;
        *(int4*)&Bh[buf][ar0][akg] = rbh;
        *(int4*)&Bl[buf][ar0][akg] = rbl;
    };

    LOADR(0);
    STORE(0);
    int cur = 0;
    for (int it = 0; it < 16; ++it) {
        if (it < 15) LOADR((it + 1) << 5);
        __syncthreads();
#pragma unroll
        for (int kh = 0; kh < 2; ++kh) {
            const int ko = (kh << 4) + (hh << 3);
            f16x8 fah[2], fal[2];
#pragma unroll
            for (int mf = 0; mf < 2; ++mf) {
                int ar = (wr << 6) + (mf << 5) + l31;
                fah[mf] = *(const f16x8*)&Ah[cur][ar][ko];
                fal[mf] = *(const f16x8*)&Al[cur][ar][ko];
            }
            int bc_ = (wc << 5) + l31;
            f16x8 bh = *(const f16x8*)&Bh[cur][bc_][ko];
            f16x8 bl = *(const f16x8*)&Bl[cur][bc_][ko];
#pragma unroll
            for (int mf = 0; mf < 2; ++mf) {
                acc1[mf] = __builtin_amdgcn_mfma_f32_32x32x16_f16(fah[mf], bh, acc1[mf], 0, 0, 0);
                acc2[mf] = __builtin_amdgcn_mfma_f32_32x32x16_f16(fah[mf], bl, acc2[mf], 0, 0, 0);
                acc2[mf] = __builtin_amdgcn_mfma_f32_32x32x16_f16(fal[mf], bh, acc2[mf], 0, 0, 0);
            }
        }
        if (it < 15) { STORE(cur ^ 1); cur ^= 1; }
    }
    const int col = bn + (wc << 5) + l31;
    const float badd = BIAS ? bias[col] : 0.f;
#pragma unroll
    for (int mf = 0; mf < 2; ++mf) {
#pragma unroll
        for (int r = 0; r < 16; ++r) {
            int row = bm + (wr << 6) + (mf << 5) + (r & 3) + ((r >> 2) << 3) + (hh << 2);
            float* cp = Cout + (size_t)row * ldc + col;
            float val = acc1[mf][r] + acc2[mf][r] * LOINV + badd;
            if (ADD_C) val += *cp;
            *cp = val;
        }
    }
}

// ---- per-row top-64: relu + exact radix select (early-exit, 1 barrier/iter) -
__global__ __launch_bounds__(256) void topk_k(const float* __restrict__ logits,
                                              float* __restrict__ out) {
    const int row = blockIdx.x;
    const float* lr = logits + (((size_t)row) << 12);
    const int t = threadIdx.x;
    float v[16]; uint32_t u[16];
#pragma unroll
    for (int i = 0; i < 16; ++i) {
        float x = fmaxf(lr[t + (i << 8)], 0.f);
        v[i] = x;
        u[i] = __float_as_uint(x);
    }
    __shared__ int red[2][4];
    __shared__ unsigned long long bits[64];
    __shared__ int s_cut;
    uint32_t prefix = 0;
    bool exact = false;
    int par = 0;
    for (int bit = 30; bit >= 0; --bit, par ^= 1) {
        uint32_t c = prefix | (1u << bit);
        int cnt = 0;
#pragma unroll
        for (int i = 0; i < 16; ++i) cnt += (u[i] >= c) ? 1 : 0;
#pragma unroll
        for (int off = 32; off; off >>= 1) cnt += __shfl_xor(cnt, off);
        if ((t & 63) == 0) red[par][t >> 6] = cnt;
        __syncthreads();
        int total = red[par][0] + red[par][1] + red[par][2] + red[par][3];
        if (total >= 64) prefix = c;
        if (total == 64) { exact = true; break; }
    }
    float* orow = out + (((size_t)row) << 12);
    if (exact) {
#pragma unroll
        for (int i = 0; i < 16; ++i) {
            int col = t + (i << 8);
            orow[col] = (u[i] >= prefix) ? v[i] : 0.f;
        }
        return;
    }
    const uint32_t T64 = prefix;
    int cg = 0;
#pragma unroll
    for (int i = 0; i < 16; ++i) cg += (u[i] > T64) ? 1 : 0;
#pragma unroll
    for (int off = 32; off; off >>= 1) cg += __shfl_xor(cg, off);
    __syncthreads();
    if ((t & 63) == 0) red[0][t >> 6] = cg;
    __syncthreads();
    const int ngt = red[0][0] + red[0][1] + red[0][2] + red[0][3];
    int cut = -1;
    if (T64 != 0u) {
        const int r = 64 - ngt;
        if (t < 64) bits[t] = 0ull;
        __syncthreads();
#pragma unroll
        for (int i = 0; i < 16; ++i) {
            if (u[i] == T64) {
                int col = t + (i << 8);
                atomicOr(&bits[col >> 6], 1ull << (col & 63));
            }
        }
        __syncthreads();
        if (t == 0) {
            int need = r, cs = FDIM - 1;
            for (int wd = 0; wd < 64; ++wd) {
                int pc = __popcll(bits[wd]);
                if (need <= pc) {
                    unsigned long long bb = bits[wd];
                    for (int q = 1; q < need; ++q) bb &= bb - 1;
                    cs = (wd << 6) + (__ffsll(bb) - 1);
                    break;
                }
                need -= pc;
            }
            s_cut = cs;
        }
        __syncthreads();
        cut = s_cut;
    }
#pragma unroll
    for (int i = 0; i < 16; ++i) {
        int col = t + (i << 8);
        bool keep = (u[i] > T64) || (T64 != 0u && u[i] == T64 && col <= cut);
        orow[col] = keep ? v[i] : 0.f;
    }
}

extern "C" void kernel_launch(void* const* d_in, const int* in_sizes, int n_in,
                              void* d_out, int out_size, void* d_ws, size_t ws_size,
                              hipStream_t stream) {
    const float* zL      = (const float*)d_in[0];
    const float* gamma_l = (const float*)d_in[5];
    const float* beta_l  = (const float*)d_in[6];
    const float* gamma_d = (const float*)d_in[11];
    const float* beta_d  = (const float*)d_in[12];
    const float* dict_e  = (const float*)d_in[13];
    const float* bias_pre= (const float*)d_in[14];
    const float* bias_enc= (const float*)d_in[15];
    const float* qt      = (const float*)d_in[16];
    const float* worder[8] = { (const float*)d_in[1], (const float*)d_in[2],
                               (const float*)d_in[3], (const float*)d_in[4],
                               (const float*)d_in[7], (const float*)d_in[8],
                               (const float*)d_in[9], (const float*)d_in[10] };

    float* out_z  = (float*)d_out;
    float* out_xp = out_z + (size_t)NTOK * FDIM;

    const size_t NHf = (size_t)NTOK * HDIM;
    float* B0 = (float*)d_out;         // residual X (z_n region)
    float* B1 = B0 + NHf;              // fused QKV [16384][1536]

    float* wsf    = (float*)d_ws;
    float* logits = wsf + 64;

    const size_t dictE = (size_t)FDIM * HDIM;
    const size_t WE    = (size_t)HDIM * HDIM;

    int crows = 4096;                  // 67 MB logits chunk (L3-resident)
    const size_t fixedB = 64 * sizeof(float)
                        + (2 * dictE + 16 * WE + 2 * NHf) * sizeof(_Float16);
    while (crows > 128 && fixedB + (size_t)crows * FDIM * sizeof(float) > ws_size)
        crows >>= 1;

    _Float16* dh  = (_Float16*)(logits + (size_t)crows * FDIM);
    _Float16* dl  = dh + dictE;
    _Float16* wsph = dh + 2 * dictE;   // 8 x WE (h), then 8 x WE (l)
    _Float16* wspl = wsph + 8 * WE;
    _Float16* xh  = wspl + 8 * WE;
    _Float16* xl  = xh + NHf;
    _Float16* qkvh_l = wsph;
    _Float16* qkvl_l = wspl;
    _Float16* woh_l  = wsph + 3 * WE;
    _Float16* wol_l  = wspl + 3 * WE;
    _Float16* qkvh_d = wsph + 4 * WE;
    _Float16* qkvl_d = wspl + 4 * WE;
    _Float16* woh_d  = wsph + 7 * WE;
    _Float16* wol_d  = wspl + 7 * WE;

    const dim3 blk256(256);
    const dim3 gElem(4096);
    const int perW = (int)(WE / 8 / 256);
    const dim3 gQKV(QKVD / 64, NTOK / 128);
    const dim3 gWo(HDIM / 64, NTOK / 128);

    split2w_k<<<dim3(8 * perW), blk256, 0, stream>>>(
        worder[0], worder[1], worder[2], worder[3],
        worder[4], worder[5], worder[6], worder[7],
        wsph, wspl, perW, (int)WE);
    split2_k<<<dim3(dictE / 8 / 256), blk256, 0, stream>>>(dict_e, dh, dl);

    // ---- layer attention block (build_x fused into first LN) ----
    ln_split_first_k<<<dim3(NTOK / 4), blk256, 0, stream>>>(zL, qt, gamma_l, beta_l, B0, xh, xl);
    gemm_f16_k<0, false, false><<<gQKV, blk256, 0, stream>>>(xh, xl, qkvh_l, qkvl_l, nullptr, B1, QKVD);
    attn_l_k<<<dim3(128, NHEAD), blk256, 0, stream>>>(B1, xh, xl);
    gemm_f16_k<0, true, false><<<gWo, blk256, 0, stream>>>(xh, xl, woh_l, wol_l, nullptr, B0, HDIM);

    // ---- depth attention block ----
    ln_split_k<<<dim3(NTOK / 4), blk256, 0, stream>>>(B0, gamma_d, beta_d, xh, xl);
    gemm_f16_k<0, false, false><<<gQKV, blk256, 0, stream>>>(xh, xl, qkvh_d, qkvl_d, nullptr, B1, QKVD);
    attn_d_k<<<dim3(1024), blk256, 0, stream>>>(B1, xh, xl);
    gemm_f16_k<0, true, false><<<gWo, blk256, 0, stream>>>(xh, xl, woh_d, wol_d, nullptr, B0, HDIM);

    // ---- x_prior out + x_src split ----
    xprior_xsrc_k<<<gElem, blk256, 0, stream>>>(zL, bias_pre, B0, out_xp, xh, xl);

    for (int c0 = 0; c0 < NTOK; c0 += crows) {
        if ((crows & 127) == 0 && (crows / 128) * 64 % 8 == 0) {
            gemm_f16_k<1, false, true><<<dim3(64 * (crows / 128)), blk256, 0, stream>>>(
                xh + (size_t)c0 * HDIM, xl + (size_t)c0 * HDIM,
                dh, dl, bias_enc, logits, FDIM);
        } else {
            gemm_f16_k<0, false, true><<<dim3(FDIM / 64, crows / 128), blk256, 0, stream>>>(
                xh + (size_t)c0 * HDIM, xl + (size_t)c0 * HDIM,
                dh, dl, bias_enc, logits, FDIM);
        }
        topk_k<<<dim3(crows), blk256, 0, stream>>>(logits, out_z + (size_t)c0 * FDIM);
    }
}